// Round 10
// baseline (883.939 us; speedup 1.0000x reference)
//
#include <hip/hip_runtime.h>
#include <hip/hip_bf16.h>
#include <math.h>

#define SEQ 2048
#define HIDD 2048
#define QRANK 1536
#define KVRANK 512
#define TOPK 512
#define EPSF 1e-6f
#define SCALE_ATTN 0.07216878364870323f  /* 192^-0.5 */
#define NCAT 1680

typedef __attribute__((ext_vector_type(8))) short short8v;
typedef __attribute__((ext_vector_type(4))) short short4v;
typedef __attribute__((ext_vector_type(4))) float f32x4;

__device__ inline unsigned short f2bf(float f) {
    unsigned u = __float_as_uint(f);
    unsigned r = (u + 0x7FFFu + ((u >> 16) & 1u)) >> 16;
    return (unsigned short)r;
}
__device__ inline float bf2f(unsigned short b) {
    return __uint_as_float(((unsigned)b) << 16);
}
__device__ inline void split2(float x, unsigned short& h, unsigned short& l) {
    h = f2bf(x);
    l = f2bf(x - bf2f(h));
}

// HW transpose read: 4 bf16 at p + j*32B (j=0..3).
__device__ inline short4v ds_read_tr16(const void* p) {
#if __has_builtin(__builtin_amdgcn_ds_read_tr16_b64)
    return __builtin_amdgcn_ds_read_tr16_b64((short4v*)p);
#else
    const unsigned short* u = (const unsigned short*)p;
    short4v r;
    r[0] = (short)u[0]; r[1] = (short)u[16]; r[2] = (short)u[32]; r[3] = (short)u[48];
    return r;
#endif
}

// ---------------- RoPE cos/sin table ----------------
__global__ void rope_table_kernel(float* __restrict__ cos_t, float* __restrict__ sin_t) {
    int s = blockIdx.x;
    int i = threadIdx.x;  // 0..31
    double inv = pow(10000.0, -((double)(2 * i)) / 64.0);
    double f = (double)s * inv;
    cos_t[s * 32 + i] = (float)cos(f);
    sin_t[s * 32 + i] = (float)sin(f);
}

// ---------------- fused f32 -> bf16 convert of 4 weight tensors ----------------
__global__ __launch_bounds__(256) void cvt_bf16_4_kernel(
    const float* __restrict__ a, int na4, const float* __restrict__ b, int nb4,
    const float* __restrict__ c, int nc4, const float* __restrict__ d, int nd4,
    unsigned short* __restrict__ oa, unsigned short* __restrict__ ob,
    unsigned short* __restrict__ oc, unsigned short* __restrict__ od)
{
    int total = na4 + nb4 + nc4 + nd4;
    for (int i = blockIdx.x * 256 + threadIdx.x; i < total; i += gridDim.x * 256) {
        const float* src; unsigned short* dst; int j = i;
        if (j < na4) { src = a; dst = oa; }
        else if ((j -= na4) < nb4) { src = b; dst = ob; }
        else if ((j -= nb4) < nc4) { src = c; dst = oc; }
        else { j -= nc4; src = d; dst = od; }
        float4 v = ((const float4*)src)[j];
        ushort4 o;
        o.x = f2bf(v.x); o.y = f2bf(v.y); o.z = f2bf(v.z); o.w = f2bf(v.w);
        ((ushort4*)dst)[j] = o;
    }
}

// ---------------- hi/lo split precompute: hidden, cat-weights (with 0.25 tail), wq ----------------
__global__ __launch_bounds__(256) void cvt_split3_kernel(
    const float* __restrict__ hidden, const float* __restrict__ q_a_w,
    const float* __restrict__ idx_wk_w, const float* __restrict__ idx_wproj_w,
    const float* __restrict__ wq,
    unsigned short* __restrict__ hidh, unsigned short* __restrict__ hidl,
    unsigned short* __restrict__ catwh, unsigned short* __restrict__ catwl,
    unsigned short* __restrict__ wqh, unsigned short* __restrict__ wql)
{
    const int nhid4 = HIDD * HIDD / 4;
    const int ncat4 = NCAT * HIDD / 4;
    const int nwq4  = HIDD * QRANK / 4;
    int total = nhid4 + ncat4 + nwq4;
    for (int i = blockIdx.x * 256 + threadIdx.x; i < total; i += gridDim.x * 256) {
        int j = i;
        const float4* s4;
        unsigned short *dh, *dl;
        float scale = 1.f;
        if (j < nhid4) {
            s4 = (const float4*)hidden + j; dh = hidh; dl = hidl;
        } else if ((j -= nhid4) < ncat4) {
            int row = (j * 4) >> 11;  // /2048
            dh = catwh; dl = catwl;
            if (row < 1536) s4 = (const float4*)q_a_w + j;
            else if (row < 1664) s4 = (const float4*)idx_wk_w + (j - 1536 * 512);
            else { s4 = (const float4*)idx_wproj_w + (j - 1664 * 512); scale = 0.25f; }
        } else {
            j -= ncat4;
            s4 = (const float4*)wq + j; dh = wqh; dl = wql;
        }
        float4 v = *s4;
        float xs[4] = {v.x * scale, v.y * scale, v.z * scale, v.w * scale};
        ushort4 oh, ol;
        unsigned short h2, l2;
        split2(xs[0], h2, l2); oh.x = h2; ol.x = l2;
        split2(xs[1], h2, l2); oh.y = h2; ol.y = l2;
        split2(xs[2], h2, l2); oh.z = h2; ol.z = l2;
        split2(xs[3], h2, l2); oh.w = h2; ol.w = l2;
        ((ushort4*)dh)[j] = oh;
        ((ushort4*)dl)[j] = ol;
    }
}

// ---------------- wkt[h][n][d] = bf16(kv_b_w[h*256+d][n]), LDS-tiled transpose ----------------
__global__ __launch_bounds__(256) void wkt_kernel(const float* __restrict__ kvb,
                                                  unsigned short* __restrict__ wkt) {
    __shared__ float t[128][129];
    int h = blockIdx.x, n0 = blockIdx.y * 128;
    int tid = threadIdx.x;
    for (int it = tid; it < 128 * 32; it += 256) {
        int d = it >> 5, c4 = it & 31;
        float4 v = *(const float4*)(kvb + ((size_t)(h * 256 + d)) * 512 + n0 + c4 * 4);
        t[d][c4 * 4 + 0] = v.x; t[d][c4 * 4 + 1] = v.y;
        t[d][c4 * 4 + 2] = v.z; t[d][c4 * 4 + 3] = v.w;
    }
    __syncthreads();
    for (int it = tid; it < 128 * 32; it += 256) {
        int n = it >> 5, dc = it & 31;
        ushort4 o;
        o.x = f2bf(t[dc * 4 + 0][n]); o.y = f2bf(t[dc * 4 + 1][n]);
        o.z = f2bf(t[dc * 4 + 2][n]); o.w = f2bf(t[dc * 4 + 3][n]);
        *(ushort4*)(wkt + ((size_t)h * 512 + n0 + n) * 128 + dc * 4) = o;
    }
}

// ---------------- split-bf16 3-pass MFMA cat-GEMM (optional precomputed operands) ----------------
__global__ __launch_bounds__(256) void gemm_cat_split_kernel(
    const float* __restrict__ hidden, const float* __restrict__ q_a_w,
    const float* __restrict__ idx_wk_w, const float* __restrict__ idx_wproj_w,
    const unsigned short* __restrict__ hidh, const unsigned short* __restrict__ hidl,
    const unsigned short* __restrict__ catwh, const unsigned short* __restrict__ catwl,
    float* __restrict__ ccat)
{
    __shared__ __align__(16) unsigned short Ah[128 * 32], Al[128 * 32];
    __shared__ __align__(16) unsigned short Bh[128 * 32], Bl[128 * 32];
    int tid = threadIdx.x;
    int l = tid & 63, w = tid >> 6;
    int wr = w >> 1, wc = w & 1;
    int m0 = blockIdx.x * 128, n0 = blockIdx.y * 128;
    const bool pre = (hidh != nullptr);
    f32x4 acc[4][4] = {};
    for (int k0 = 0; k0 < HIDD; k0 += 32) {
        __syncthreads();
#pragma unroll
        for (int i = 0; i < 2; ++i) {
            int idx = tid + i * 256;
            int r = idx >> 2, cc = idx & 3;
            int sw = cc ^ (r & 3);
            int gb = n0 + r; if (gb > NCAT - 1) gb = NCAT - 1;
            if (pre) {
                size_t abase = (size_t)(m0 + r) * HIDD + k0 + cc * 8;
                *(short8v*)&Ah[r * 32 + sw * 8] = *(const short8v*)(hidh + abase);
                *(short8v*)&Al[r * 32 + sw * 8] = *(const short8v*)(hidl + abase);
                size_t bbase = (size_t)gb * HIDD + k0 + cc * 8;
                *(short8v*)&Bh[r * 32 + sw * 8] = *(const short8v*)(catwh + bbase);
                *(short8v*)&Bl[r * 32 + sw * 8] = *(const short8v*)(catwl + bbase);
            } else {
                {
                    const float* src = hidden + (size_t)(m0 + r) * HIDD + k0 + cc * 8;
                    float4 f0 = *(const float4*)src, f1 = *(const float4*)(src + 4);
                    float xs[8] = {f0.x, f0.y, f0.z, f0.w, f1.x, f1.y, f1.z, f1.w};
                    short8v dh, dl;
#pragma unroll
                    for (int e = 0; e < 8; ++e) {
                        unsigned short hh, ll; split2(xs[e], hh, ll);
                        dh[e] = (short)hh; dl[e] = (short)ll;
                    }
                    *(short8v*)&Ah[r * 32 + sw * 8] = dh;
                    *(short8v*)&Al[r * 32 + sw * 8] = dl;
                }
                {
                    float scale = 1.f;
                    const float* src;
                    if (gb < 1536) src = q_a_w + (size_t)gb * HIDD;
                    else if (gb < 1664) src = idx_wk_w + (size_t)(gb - 1536) * HIDD;
                    else { src = idx_wproj_w + (size_t)(gb - 1664) * HIDD; scale = 0.25f; }
                    src += k0 + cc * 8;
                    float4 f0 = *(const float4*)src, f1 = *(const float4*)(src + 4);
                    float xs[8] = {f0.x, f0.y, f0.z, f0.w, f1.x, f1.y, f1.z, f1.w};
                    short8v dh, dl;
#pragma unroll
                    for (int e = 0; e < 8; ++e) {
                        unsigned short hh, ll; split2(xs[e] * scale, hh, ll);
                        dh[e] = (short)hh; dl[e] = (short)ll;
                    }
                    *(short8v*)&Bh[r * 32 + sw * 8] = dh;
                    *(short8v*)&Bl[r * 32 + sw * 8] = dl;
                }
            }
        }
        __syncthreads();
        short8v avh[4], avl[4];
#pragma unroll
        for (int mt = 0; mt < 4; ++mt) {
            int row = wr * 64 + mt * 16 + (l & 15);
            int ch = (l >> 4) ^ (row & 3);
            avh[mt] = *(const short8v*)&Ah[row * 32 + ch * 8];
            avl[mt] = *(const short8v*)&Al[row * 32 + ch * 8];
        }
#pragma unroll
        for (int nt = 0; nt < 4; ++nt) {
            int row = wc * 64 + nt * 16 + (l & 15);
            int ch = (l >> 4) ^ (row & 3);
            short8v bvh = *(const short8v*)&Bh[row * 32 + ch * 8];
            short8v bvl = *(const short8v*)&Bl[row * 32 + ch * 8];
#pragma unroll
            for (int mt = 0; mt < 4; ++mt) {
                acc[mt][nt] = __builtin_amdgcn_mfma_f32_16x16x32_bf16(avh[mt], bvh, acc[mt][nt], 0, 0, 0);
                acc[mt][nt] = __builtin_amdgcn_mfma_f32_16x16x32_bf16(avh[mt], bvl, acc[mt][nt], 0, 0, 0);
                acc[mt][nt] = __builtin_amdgcn_mfma_f32_16x16x32_bf16(avl[mt], bvh, acc[mt][nt], 0, 0, 0);
            }
        }
    }
#pragma unroll
    for (int mt = 0; mt < 4; ++mt)
#pragma unroll
        for (int nt = 0; nt < 4; ++nt)
#pragma unroll
            for (int i = 0; i < 4; ++i) {
                int gm = m0 + wr * 64 + mt * 16 + (l >> 4) * 4 + i;
                int gn = n0 + wc * 64 + nt * 16 + (l & 15);
                if (gn < NCAT) ccat[(size_t)gm * NCAT + gn] = acc[mt][nt][i];
            }
}

// ---------------- split-bf16 3-pass MFMA iq-GEMM, fused RoPE + hi/lo split output ----------------
__global__ __launch_bounds__(256) void gemm_iq_split_kernel(
    const float* __restrict__ qr, const float* __restrict__ wq,
    const unsigned short* __restrict__ qrh, const unsigned short* __restrict__ qrl,
    const unsigned short* __restrict__ wqh, const unsigned short* __restrict__ wql,
    const float* __restrict__ cos_t, const float* __restrict__ sin_t,
    unsigned short* __restrict__ iqh, unsigned short* __restrict__ iql)
{
    __shared__ __align__(16) unsigned short Ah[128 * 32], Al[128 * 32];
    __shared__ __align__(16) unsigned short Bh[128 * 32], Bl[128 * 32];
    int tid = threadIdx.x;
    int l = tid & 63, w = tid >> 6;
    int wr = w >> 1, wc = w & 1;
    int m0 = blockIdx.x * 128, n0 = blockIdx.y * 128;
    int hh_ = blockIdx.y;  // head
    const bool pre = (wqh != nullptr);
    f32x4 acc[4][4] = {};
    for (int k0 = 0; k0 < QRANK; k0 += 32) {
        __syncthreads();
#pragma unroll
        for (int i = 0; i < 2; ++i) {
            int idx = tid + i * 256;
            int r = idx >> 2, cc = idx & 3;
            int sw = cc ^ (r & 3);
            if (pre) {
                size_t abase = (size_t)(m0 + r) * QRANK + k0 + cc * 8;
                *(short8v*)&Ah[r * 32 + sw * 8] = *(const short8v*)(qrh + abase);
                *(short8v*)&Al[r * 32 + sw * 8] = *(const short8v*)(qrl + abase);
                size_t bbase = (size_t)(n0 + r) * QRANK + k0 + cc * 8;
                *(short8v*)&Bh[r * 32 + sw * 8] = *(const short8v*)(wqh + bbase);
                *(short8v*)&Bl[r * 32 + sw * 8] = *(const short8v*)(wql + bbase);
            } else {
                {
                    const float* src = qr + (size_t)(m0 + r) * QRANK + k0 + cc * 8;
                    float4 f0 = *(const float4*)src, f1 = *(const float4*)(src + 4);
                    float xs[8] = {f0.x, f0.y, f0.z, f0.w, f1.x, f1.y, f1.z, f1.w};
                    short8v dh, dl;
#pragma unroll
                    for (int e = 0; e < 8; ++e) {
                        unsigned short h2, l2; split2(xs[e], h2, l2);
                        dh[e] = (short)h2; dl[e] = (short)l2;
                    }
                    *(short8v*)&Ah[r * 32 + sw * 8] = dh;
                    *(short8v*)&Al[r * 32 + sw * 8] = dl;
                }
                {
                    const float* src = wq + (size_t)(n0 + r) * QRANK + k0 + cc * 8;
                    float4 f0 = *(const float4*)src, f1 = *(const float4*)(src + 4);
                    float xs[8] = {f0.x, f0.y, f0.z, f0.w, f1.x, f1.y, f1.z, f1.w};
                    short8v dh, dl;
#pragma unroll
                    for (int e = 0; e < 8; ++e) {
                        unsigned short h2, l2; split2(xs[e], h2, l2);
                        dh[e] = (short)h2; dl[e] = (short)l2;
                    }
                    *(short8v*)&Bh[r * 32 + sw * 8] = dh;
                    *(short8v*)&Bl[r * 32 + sw * 8] = dl;
                }
            }
        }
        __syncthreads();
        short8v avh[4], avl[4];
#pragma unroll
        for (int mt = 0; mt < 4; ++mt) {
            int row = wr * 64 + mt * 16 + (l & 15);
            int ch = (l >> 4) ^ (row & 3);
            avh[mt] = *(const short8v*)&Ah[row * 32 + ch * 8];
            avl[mt] = *(const short8v*)&Al[row * 32 + ch * 8];
        }
#pragma unroll
        for (int nt = 0; nt < 4; ++nt) {
            int row = wc * 64 + nt * 16 + (l & 15);
            int ch = (l >> 4) ^ (row & 3);
            short8v bvh = *(const short8v*)&Bh[row * 32 + ch * 8];
            short8v bvl = *(const short8v*)&Bl[row * 32 + ch * 8];
#pragma unroll
            for (int mt = 0; mt < 4; ++mt) {
                acc[mt][nt] = __builtin_amdgcn_mfma_f32_16x16x32_bf16(avh[mt], bvh, acc[mt][nt], 0, 0, 0);
                acc[mt][nt] = __builtin_amdgcn_mfma_f32_16x16x32_bf16(avh[mt], bvl, acc[mt][nt], 0, 0, 0);
                acc[mt][nt] = __builtin_amdgcn_mfma_f32_16x16x32_bf16(avl[mt], bvh, acc[mt][nt], 0, 0, 0);
            }
        }
    }
    if (wc == 0) {
#pragma unroll
        for (int mt = 0; mt < 4; ++mt)
#pragma unroll
            for (int nt = 0; nt < 2; ++nt)
#pragma unroll
                for (int i = 0; i < 4; ++i) {
                    int q = m0 + wr * 64 + mt * 16 + (l >> 4) * 4 + i;
                    int dd = nt * 16 + (l & 15);
                    float c = cos_t[q * 32 + dd], s = sin_t[q * 32 + dd];
                    float x1 = acc[mt][nt][i], x2 = acc[mt][nt + 2][i];
                    acc[mt][nt][i] = x1 * c - x2 * s;
                    acc[mt][nt + 2][i] = x2 * c + x1 * s;
                }
    }
#pragma unroll
    for (int mt = 0; mt < 4; ++mt)
#pragma unroll
        for (int nt = 0; nt < 4; ++nt)
#pragma unroll
            for (int i = 0; i < 4; ++i) {
                int q = m0 + wr * 64 + mt * 16 + (l >> 4) * 4 + i;
                int d = wc * 64 + nt * 16 + (l & 15);
                size_t idx = ((size_t)q * 16 + hh_) * 128 + d;
                unsigned short h2, l2; split2(acc[mt][nt][i], h2, l2);
                iqh[idx] = h2; iql[idx] = l2;
            }
}

// ---------------- bf16 MFMA NT GEMM, batched, optional fused RoPE epilogue ----------------
template <typename TA, typename TC>
__global__ __launch_bounds__(256) void mfma_nt_kernel(
    const TA* __restrict__ A, const unsigned short* __restrict__ B, TC* __restrict__ C,
    int M, int N, int K, int lda, int ldb, int ldc, long ab, long bb, long cb,
    const float* __restrict__ cos_t, const float* __restrict__ sin_t, int rope_mode)
{
    __shared__ __align__(16) unsigned short Asl[128 * 32];
    __shared__ __align__(16) unsigned short Bsl[128 * 32];
    int z = blockIdx.z;
    const TA* Az = A + (size_t)z * ab;
    const unsigned short* Bz = B + (size_t)z * bb;
    TC* Cz = C + (size_t)z * cb;
    int tid = threadIdx.x;
    int l = tid & 63, w = tid >> 6;
    int wr = w >> 1, wc = w & 1;
    int m0 = blockIdx.x * 128, n0 = blockIdx.y * 128;
    f32x4 acc[4][4] = {};

    for (int k0 = 0; k0 < K; k0 += 32) {
        __syncthreads();
#pragma unroll
        for (int i = 0; i < 2; ++i) {
            int idx = tid + i * 256;
            int r = idx >> 2, cc = idx & 3;
            int sw = cc ^ (r & 3);
            {
                short8v d;
                const TA* src = Az + (size_t)(m0 + r) * lda + k0 + cc * 8;
                if constexpr (sizeof(TA) == 2) {
                    d = *(const short8v*)src;
                } else {
                    float4 f0 = *(const float4*)src;
                    float4 f1 = *(const float4*)(src + 4);
                    d[0] = (short)f2bf(f0.x); d[1] = (short)f2bf(f0.y);
                    d[2] = (short)f2bf(f0.z); d[3] = (short)f2bf(f0.w);
                    d[4] = (short)f2bf(f1.x); d[5] = (short)f2bf(f1.y);
                    d[6] = (short)f2bf(f1.z); d[7] = (short)f2bf(f1.w);
                }
                *(short8v*)&Asl[r * 32 + sw * 8] = d;
            }
            {
                int gb = n0 + r; if (gb > N - 1) gb = N - 1;
                short8v d = *(const short8v*)(Bz + (size_t)gb * ldb + k0 + cc * 8);
                *(short8v*)&Bsl[r * 32 + sw * 8] = d;
            }
        }
        __syncthreads();
        short8v av[4], bv[4];
#pragma unroll
        for (int mt = 0; mt < 4; ++mt) {
            int row = wr * 64 + mt * 16 + (l & 15);
            int ch = (l >> 4) ^ (row & 3);
            av[mt] = *(const short8v*)&Asl[row * 32 + ch * 8];
        }
#pragma unroll
        for (int nt = 0; nt < 4; ++nt) {
            int row = wc * 64 + nt * 16 + (l & 15);
            int ch = (l >> 4) ^ (row & 3);
            bv[nt] = *(const short8v*)&Bsl[row * 32 + ch * 8];
        }
#pragma unroll
        for (int mt = 0; mt < 4; ++mt)
#pragma unroll
            for (int nt = 0; nt < 4; ++nt)
                acc[mt][nt] = __builtin_amdgcn_mfma_f32_16x16x32_bf16(av[mt], bv[nt], acc[mt][nt], 0, 0, 0);
    }
    if (rope_mode) {
        int gcol64 = (n0 >> 6) + wc;
        bool dorope = (rope_mode == 1) ? ((gcol64 % 3) == 2) : (gcol64 == 8);
        if (dorope) {
#pragma unroll
            for (int mt = 0; mt < 4; ++mt)
#pragma unroll
                for (int nt = 0; nt < 2; ++nt)
#pragma unroll
                    for (int i = 0; i < 4; ++i) {
                        int q = m0 + wr * 64 + mt * 16 + (l >> 4) * 4 + i;
                        int dd = nt * 16 + (l & 15);
                        float c = cos_t[q * 32 + dd], sn = sin_t[q * 32 + dd];
                        float x1 = acc[mt][nt][i], x2 = acc[mt][nt + 2][i];
                        acc[mt][nt][i] = x1 * c - x2 * sn;
                        acc[mt][nt + 2][i] = x2 * c + x1 * sn;
                    }
        }
    }
#pragma unroll
    for (int mt = 0; mt < 4; ++mt) {
#pragma unroll
        for (int nt = 0; nt < 4; ++nt) {
#pragma unroll
            for (int i = 0; i < 4; ++i) {
                int gm = m0 + wr * 64 + mt * 16 + (l >> 4) * 4 + i;
                int gn = n0 + wc * 64 + nt * 16 + (l & 15);
                if (gn < N) {
                    float v = acc[mt][nt][i];
                    if constexpr (sizeof(TC) == 4) Cz[(size_t)gm * ldc + gn] = v;
                    else Cz[(size_t)gm * ldc + gn] = f2bf(v);
                }
            }
        }
    }
}

// ---------------- RMSNorm (qr path), bf16 hi + optional lo outputs ----------------
__global__ __launch_bounds__(256) void rmsnorm_kernel(
    const float* __restrict__ in, const float* __restrict__ w, float* __restrict__ out,
    unsigned short* __restrict__ bf_out, unsigned short* __restrict__ bf_lo,
    int n, int in_stride)
{
    int row = blockIdx.x, tid = threadIdx.x;
    const float* x = in + (size_t)row * in_stride;
    float4 v[2];
    int cnt = 0;
    float ss = 0.f;
    int nf4 = n >> 2;
    for (int i = tid; i < nf4; i += 256) {
        float4 t = *(const float4*)(x + i * 4);
        v[cnt++] = t;
        ss += t.x * t.x + t.y * t.y + t.z * t.z + t.w * t.w;
    }
#pragma unroll
    for (int m = 32; m; m >>= 1) ss += __shfl_xor(ss, m);
    __shared__ float red[8];
    int wid = tid >> 6;
    if ((tid & 63) == 0) red[wid] = ss;
    __syncthreads();
    if (tid == 0) {
        float s = red[0] + red[1] + red[2] + red[3];
        red[4] = rsqrtf(s / (float)n + EPSF);
    }
    __syncthreads();
    float scale = red[4];
    cnt = 0;
    for (int i = tid; i < nf4; i += 256) {
        float4 t = v[cnt++];
        float4 wv = *(const float4*)(w + i * 4);
        float4 o;
        o.x = t.x * scale * wv.x; o.y = t.y * scale * wv.y;
        o.z = t.z * scale * wv.z; o.w = t.w * scale * wv.w;
        *(float4*)(out + (size_t)row * n + i * 4) = o;
        if (bf_out) {
            ushort4 ob;
            ob.x = f2bf(o.x); ob.y = f2bf(o.y); ob.z = f2bf(o.z); ob.w = f2bf(o.w);
            *(ushort4*)(bf_out + (size_t)row * n + i * 4) = ob;
            if (bf_lo) {
                ushort4 ol;
                ol.x = f2bf(o.x - bf2f(ob.x)); ol.y = f2bf(o.y - bf2f(ob.y));
                ol.z = f2bf(o.z - bf2f(ob.z)); ol.w = f2bf(o.w - bf2f(ob.w));
                *(ushort4*)(bf_lo + (size_t)row * n + i * 4) = ol;
            }
        }
    }
}

// ---------------- fused RMSNorm(ckv[:512]) -> khg[0:512] bf16, + kpe copy -> khg[512:576] ----------------
__global__ __launch_bounds__(256) void rmsnorm_khg_kernel(
    const float* __restrict__ ckv, const float* __restrict__ w,
    unsigned short* __restrict__ khg)
{
    int row = blockIdx.x, tid = threadIdx.x;
    const float* x = ckv + (size_t)row * 576;
    float4 v = make_float4(0.f, 0.f, 0.f, 0.f);
    float ss = 0.f;
    if (tid < 128) {
        v = *(const float4*)(x + tid * 4);
        ss = v.x * v.x + v.y * v.y + v.z * v.z + v.w * v.w;
    }
#pragma unroll
    for (int mm = 32; mm; mm >>= 1) ss += __shfl_xor(ss, mm);
    __shared__ float red[8];
    if ((tid & 63) == 0) red[tid >> 6] = ss;
    __syncthreads();
    if (tid == 0) red[4] = rsqrtf((red[0] + red[1] + red[2] + red[3]) * (1.f / 512.f) + EPSF);
    __syncthreads();
    float scale = red[4];
    if (tid < 128) {
        float4 wv = *(const float4*)(w + tid * 4);
        ushort4 ob;
        ob.x = f2bf(v.x * scale * wv.x); ob.y = f2bf(v.y * scale * wv.y);
        ob.z = f2bf(v.z * scale * wv.z); ob.w = f2bf(v.w * scale * wv.w);
        *(ushort4*)(khg + (size_t)row * 576 + tid * 4) = ob;
    } else if (tid < 192) {
        khg[(size_t)row * 576 + 512 + (tid - 128)] = f2bf(x[512 + tid - 128]);
    }
}

// ---------------- LayerNorm + RoPE + hi/lo split for ik ----------------
__global__ __launch_bounds__(64) void ln_rope_split_kernel(
    const float* __restrict__ in, int stride,
    const float* __restrict__ w, const float* __restrict__ b,
    const float* __restrict__ cos_t, const float* __restrict__ sin_t,
    unsigned short* __restrict__ ikh, unsigned short* __restrict__ ikl)
{
    int row = blockIdx.x, tid = threadIdx.x;
    const float* x = in + (size_t)row * stride;
    float x0 = x[tid], x1 = x[tid + 64];
    float s = x0 + x1, ss = x0 * x0 + x1 * x1;
#pragma unroll
    for (int m = 32; m; m >>= 1) { s += __shfl_xor(s, m); ss += __shfl_xor(ss, m); }
    float mean = s * (1.f / 128.f);
    float var = ss * (1.f / 128.f) - mean * mean;
    float r = rsqrtf(var + EPSF);
    float n0 = (x0 - mean) * r * w[tid] + b[tid];
    float n1 = (x1 - mean) * r * w[tid + 64] + b[tid + 64];
    float c = cos_t[row * 32 + (tid & 31)], sn = sin_t[row * 32 + (tid & 31)];
    float other = __shfl_xor(n0, 32);
    float r0 = (tid < 32) ? (n0 * c - other * sn) : (n0 * c + other * sn);
    unsigned short h2, l2;
    split2(r0, h2, l2);
    ikh[(size_t)row * 128 + tid] = h2; ikl[(size_t)row * 128 + tid] = l2;
    split2(n1, h2, l2);
    ikh[(size_t)row * 128 + 64 + tid] = h2; ikl[(size_t)row * 128 + 64 + tid] = l2;
}

// ---------------- indexer scores via split-bf16 3-pass MFMA (B-frags hoisted to regs) ----------------
__global__ __launch_bounds__(256) void idx_scores_mfma_kernel(
    const unsigned short* __restrict__ iqh, const unsigned short* __restrict__ iql,
    const unsigned short* __restrict__ ikh, const unsigned short* __restrict__ ikl,
    const float* __restrict__ iwsrc, int iw_stride,
    float* __restrict__ scores)
{
    int q0 = blockIdx.x * 64, k0 = blockIdx.y * 64;
    int tid = threadIdx.x;
    if (k0 > q0 + 63) {
        for (int t = tid; t < 64 * 64; t += 256) {
            int r = t >> 6, c = t & 63;
            scores[(size_t)(q0 + r) * SEQ + k0 + c] = -INFINITY;
        }
        return;
    }
    __shared__ __align__(16) unsigned short skh[64 * 128], skl[64 * 128];
    __shared__ __align__(16) unsigned short sqh[64 * 128], sql[64 * 128];
    __shared__ float iws[64][16];
    int l = tid & 63, w = tid >> 6;
    for (int it = tid; it < 64 * 16; it += 256) {
        int r = it >> 4, c = it & 15;
        int sw = c ^ (r & 15);
        *(short8v*)&skh[r * 128 + sw * 8] = *(const short8v*)(ikh + (size_t)(k0 + r) * 128 + c * 8);
        *(short8v*)&skl[r * 128 + sw * 8] = *(const short8v*)(ikl + (size_t)(k0 + r) * 128 + c * 8);
    }
    {
        int r = tid >> 2, c = tid & 3;
        *(float4*)&iws[r][c * 4] = *(const float4*)(iwsrc + (size_t)(q0 + r) * iw_stride + c * 4);
    }
    __syncthreads();
    short8v bhr[4][4], blr[4][4];  // [nt][ks]
#pragma unroll
    for (int nt = 0; nt < 4; ++nt)
#pragma unroll
        for (int ks = 0; ks < 4; ++ks) {
            int brow = nt * 16 + (l & 15);
            int bch = ((l >> 4) + ks * 4) ^ (brow & 15);
            bhr[nt][ks] = *(const short8v*)&skh[brow * 128 + bch * 8];
            blr[nt][ks] = *(const short8v*)&skl[brow * 128 + bch * 8];
        }
    f32x4 acc[4] = {};
    for (int h = 0; h < 16; ++h) {
        __syncthreads();
        for (int it = tid; it < 64 * 16; it += 256) {
            int r = it >> 4, c = it & 15;
            int sw = c ^ (r & 15);
            size_t base = ((size_t)(q0 + r) * 16 + h) * 128 + c * 8;
            *(short8v*)&sqh[r * 128 + sw * 8] = *(const short8v*)(iqh + base);
            *(short8v*)&sql[r * 128 + sw * 8] = *(const short8v*)(iql + base);
        }
        __syncthreads();
        f32x4 dot[4] = {};
#pragma unroll
        for (int ks = 0; ks < 4; ++ks) {
            int arow = w * 16 + (l & 15);
            int ach = ((l >> 4) + ks * 4) ^ (arow & 15);
            short8v ah = *(const short8v*)&sqh[arow * 128 + ach * 8];
            short8v al = *(const short8v*)&sql[arow * 128 + ach * 8];
#pragma unroll
            for (int nt = 0; nt < 4; ++nt) {
                dot[nt] = __builtin_amdgcn_mfma_f32_16x16x32_bf16(ah, bhr[nt][ks], dot[nt], 0, 0, 0);
                dot[nt] = __builtin_amdgcn_mfma_f32_16x16x32_bf16(ah, blr[nt][ks], dot[nt], 0, 0, 0);
                dot[nt] = __builtin_amdgcn_mfma_f32_16x16x32_bf16(al, bhr[nt][ks], dot[nt], 0, 0, 0);
            }
        }
#pragma unroll
        for (int nt = 0; nt < 4; ++nt)
#pragma unroll
            for (int i = 0; i < 4; ++i) {
                float wv = iws[w * 16 + (l >> 4) * 4 + i][h];
                acc[nt][i] += wv * fmaxf(dot[nt][i], 0.f);
            }
    }
#pragma unroll
    for (int nt = 0; nt < 4; ++nt)
#pragma unroll
        for (int i = 0; i < 4; ++i) {
            int q = q0 + w * 16 + (l >> 4) * 4 + i;
            int k = k0 + nt * 16 + (l & 15);
            scores[(size_t)q * SEQ + k] = (k <= q) ? acc[nt][i] : -INFINITY;
        }
}

// ---------------- top-512 per row via bitonic sort ----------------
__global__ __launch_bounds__(1024) void topk_kernel(
    const float* __restrict__ scores, int* __restrict__ sel)
{
    int qi = blockIdx.x, tid = threadIdx.x;
    __shared__ unsigned long long keys[2048];
    const float* srow = scores + (size_t)qi * SEQ;
#pragma unroll
    for (int r = 0; r < 2; ++r) {
        int k = tid + r * 1024;
        unsigned u = __float_as_uint(srow[k]);
        unsigned mv = (u & 0x80000000u) ? ~u : (u | 0x80000000u);
        keys[k] = ((unsigned long long)mv << 32) | (unsigned)(2047 - k);
    }
    for (int ksz = 2; ksz <= 2048; ksz <<= 1) {
        for (int j = ksz >> 1; j > 0; j >>= 1) {
            __syncthreads();
#pragma unroll 1
            for (int r = 0; r < 2; ++r) {
                int i = tid + r * 1024;
                int ixj = i ^ j;
                if (ixj > i) {
                    unsigned long long a = keys[i], b = keys[ixj];
                    bool dir = ((i & ksz) == 0);
                    if ((a < b) == dir) { keys[i] = b; keys[ixj] = a; }
                }
            }
        }
    }
    __syncthreads();
    if (tid < TOPK) {
        int k = 2047 - (int)(keys[tid] & 0xFFFFFFFFu);
        sel[(size_t)qi * TOPK + tid] = (tid <= qi) ? k : -1;
    }
}

// ---------------- MFMA flash attention: 64-key tiles, tr_b16 PV, async reg-staged prefetch (T14) ----------------
// LDS layout:
//   [0, 66560)       : V subtiled [32 dblocks][64 keys][16 d] bf16, dblock stride 2080B (+32B pad)
//   [66560, 74752)   : kpe row-major [64][64] bf16, XOR-swizzled byte^((key&7)<<4)
//   [74752, 76800)   : plds [64 keys][16 heads] bf16
//   [76800, 77312)   : smax[4][16], ssum[4][16]
__global__ __launch_bounds__(256) void attn_mfma_kernel(
    const unsigned short* __restrict__ qabs,  // (S,16,512) bf16
    const float* __restrict__ qsrc,           // qbuf (S,16,192) f32, qpe at +128
    const unsigned short* __restrict__ khg,   // (S,576) bf16: [ckvn|kpe]
    const int* __restrict__ sel,              // (S,512)
    unsigned short* __restrict__ ocomp)       // (S,16,512) bf16 normalized
{
    __shared__ __align__(16) char smem[77312];
    unsigned short* plds = (unsigned short*)(smem + 74752);
    float* smax = (float*)(smem + 76800);   // [4][16]
    float* ssum = (float*)(smem + 77056);   // [4][16]

    const int qi = blockIdx.x;
    const int tid = threadIdx.x;
    const int l = tid & 63, w = tid >> 6;
    const int lg = l >> 4, lr = l & 15;
    const int nv = min(TOPK, qi + 1);
    const int ntile = (nv + 63) >> 6;
    const int krow = w * 16 + lr;

    // static per-thread staging roles
    const int ck = tid >> 6, cc = tid & 63;   // ckvn: chunk cc of keys ck+4j (j=0..15)
    const int pk = tid >> 3, pc = tid & 7;    // kpe:  chunk pc of keys pk+32j (j=0..1)
    const int* selrow = sel + (size_t)qi * TOPK;

    // A-fragments: head = lr, k-dims lg*8 + ks*32
    short8v aq[18];
    {
        const unsigned short* qa = qabs + ((size_t)qi * 16 + lr) * 512 + lg * 8;
#pragma unroll
        for (int ks = 0; ks < 16; ++ks)
            aq[ks] = *(const short8v*)(qa + ks * 32);
        const float* qp = qsrc + (size_t)qi * 3072 + lr * 192 + 128 + lg * 8;
#pragma unroll
        for (int ks = 0; ks < 2; ++ks) {
            float4 f0 = *(const float4*)(qp + ks * 32);
            float4 f1 = *(const float4*)(qp + ks * 32 + 4);
            short8v d;
            d[0] = (short)f2bf(f0.x); d[1] = (short)f2bf(f0.y);
            d[2] = (short)f2bf(f0.z); d[3] = (short)f2bf(f0.w);
            d[4] = (short)f2bf(f1.x); d[5] = (short)f2bf(f1.y);
            d[6] = (short)f2bf(f1.z); d[7] = (short)f2bf(f1.w);
            aq[16 + ks] = d;
        }
    }

    // prologue: prefetch tile 0 into registers
    short8v vreg[16], preg[2];
#pragma unroll
    for (int j = 0; j < 16; ++j) {
        int sv = selrow[ck + 4 * j];
        if (sv < 0) sv = 0;
        vreg[j] = *(const short8v*)(khg + (size_t)sv * 576 + cc * 8);
    }
#pragma unroll
    for (int j = 0; j < 2; ++j) {
        int sv = selrow[pk + 32 * j];
        if (sv < 0) sv = 0;
        preg[j] = *(const short8v*)(khg + (size_t)sv * 576 + 512 + pc * 8);
    }

    // byte base for score-phase V reads: key=krow, dblock=(lg>>1), 16B half=(lg&1)
    const int sbase = krow * 32 + (lg >> 1) * 2080 + (lg & 1) * 16;
    // byte base for tr_b16 PV reads: dblock = w*8 (+nt), key0 = lg*8 (+kb*32), col = lr
    const int vboff = w * 16640 + lg * 256 + lr * 2;

    float m[4] = {-1e30f, -1e30f, -1e30f, -1e30f};
    float lsum[4] = {0.f, 0.f, 0.f, 0.f};
    f32x4 oacc[8] = {};

    for (int t = 0; t < ntile; ++t) {
        const int j0 = t * 64;
        __syncthreads();   // previous tile's LDS reads complete
        // write prefetched registers to LDS
#pragma unroll
        for (int j = 0; j < 16; ++j) {
            int key = ck + 4 * j;
            *(short8v*)(smem + (cc >> 1) * 2080 + key * 32 + (cc & 1) * 16) = vreg[j];
        }
#pragma unroll
        for (int j = 0; j < 2; ++j) {
            int key = pk + 32 * j;
            *(short8v*)(smem + 66560 + ((key * 128 + pc * 16) ^ ((key & 7) << 4))) = preg[j];
        }
        __syncthreads();
        // issue next tile's gathers (complete during this tile's compute)
        if (t + 1 < ntile) {
            int j1 = j0 + 64;
#pragma unroll
            for (int j = 0; j < 16; ++j) {
                int sv = selrow[j1 + ck + 4 * j];
                if (sv < 0) sv = 0;
                vreg[j] = *(const short8v*)(khg + (size_t)sv * 576 + cc * 8);
            }
#pragma unroll
            for (int j = 0; j < 2; ++j) {
                int sv = selrow[j1 + pk + 32 * j];
                if (sv < 0) sv = 0;
                preg[j] = *(const short8v*)(khg + (size_t)sv * 576 + 512 + pc * 8);
            }
        }
        // scores for wave's 16 keys
        f32x4 s = {};
#pragma unroll
        for (int ks = 0; ks < 16; ++ks) {
            short8v b = *(const short8v*)(smem + sbase + ks * 4160);
            s = __builtin_amdgcn_mfma_f32_16x16x32_bf16(aq[ks], b, s, 0, 0, 0);
        }
#pragma unroll
        for (int ks = 0; ks < 2; ++ks) {
            short8v b = *(const short8v*)(smem + 66560 +
                ((krow * 128 + ks * 64 + lg * 16) ^ ((krow & 7) << 4)));
            s = __builtin_amdgcn_mfma_f32_16x16x32_bf16(aq[16 + ks], b, s, 0, 0, 0);
        }
        bool kvalid = (j0 + krow) < nv;
#pragma unroll
        for (int i = 0; i < 4; ++i)
            s[i] = kvalid ? s[i] * SCALE_ATTN : -1e30f;
        float tm[4];
#pragma unroll
        for (int i = 0; i < 4; ++i) tm[i] = s[i];
#pragma unroll
        for (int sh = 1; sh < 16; sh <<= 1)
#pragma unroll
            for (int i = 0; i < 4; ++i) tm[i] = fmaxf(tm[i], __shfl_xor(tm[i], sh));
        if (lr == 0) *(float4*)&smax[w * 16 + lg * 4] = make_float4(tm[0], tm[1], tm[2], tm[3]);
        __syncthreads();
        float mn[4], scl[4];
#pragma unroll
        for (int i = 0; i < 4; ++i) {
            int h = lg * 4 + i;
            float tmax = fmaxf(fmaxf(smax[h], smax[16 + h]), fmaxf(smax[32 + h], smax[48 + h]));
            mn[i] = fmaxf(m[i], tmax);
            scl[i] = __expf(m[i] - mn[i]);
            m[i] = mn[i];
        }
        float p[4], rs[4];
#pragma unroll
        for (int i = 0; i < 4; ++i) { p[i] = __expf(s[i] - mn[i]); rs[i] = p[i]; }
#pragma unroll
        for (int sh = 1; sh < 16; sh <<= 1)
#pragma unroll
            for (int i = 0; i < 4; ++i) rs[i] += __shfl_xor(rs[i], sh);
        if (lr == 0) *(float4*)&ssum[w * 16 + lg * 4] = make_float4(rs[0], rs[1], rs[2], rs[3]);
        {
            ushort4 pb;
            pb.x = f2bf(p[0]); pb.y = f2bf(p[1]); pb.z = f2bf(p[2]); pb.w = f2bf(p[3]);
            *(ushort4*)&plds[(w * 16 + lr) * 16 + lg * 4] = pb;
        }
        __syncthreads();
#pragma unroll
        for (int i = 0; i < 4; ++i) {
            int h = lg * 4 + i;
            float ts = ssum[h] + ssum[16 + h] + ssum[32 + h] + ssum[48 + h];
            lsum[i] = lsum[i] * scl[i] + ts;
        }
#pragma unroll
        for (int nt = 0; nt < 8; ++nt)
#pragma unroll
            for (int i = 0; i < 4; ++i) oacc[nt][i] *= scl[i];
        // PV: wave handles dims [w*128, w*128+128); B-frags via ds_read_tr16 (HW transpose)
#pragma unroll
        for (int kb = 0; kb < 2; ++kb) {
            short8v af;
#pragma unroll
            for (int j = 0; j < 8; ++j)
                af[j] = (short)plds[(kb * 32 + lg * 8 + j) * 16 + lr];
#pragma unroll
            for (int nt = 0; nt < 8; ++nt) {
                const char* a = smem + vboff + kb * 1024 + nt * 2080;
                short4v t0 = ds_read_tr16(a);          // keys +0..3  (elem j at +32B)
                short4v t1 = ds_read_tr16(a + 128);    // keys +4..7
                short8v bf = __builtin_shufflevector(t0, t1, 0, 1, 2, 3, 4, 5, 6, 7);
                oacc[nt] = __builtin_amdgcn_mfma_f32_16x16x32_bf16(af, bf, oacc[nt], 0, 0, 0);
            }
        }
    }
    float inv[4];
#pragma unroll
    for (int i = 0; i < 4; ++i) inv[i] = 1.f / lsum[i];
    unsigned short* ob = ocomp + (size_t)qi * 16 * 512;
#pragma unroll
    for (int nt = 0; nt < 8; ++nt) {
        int d = w * 128 + nt * 16 + lr;
#pragma unroll
        for (int i = 0; i < 4; ++i) {
            int h = lg * 4 + i;
            ob[h * 512 + d] = f2bf(oacc[nt][i] * inv[i]);
        }
    }
}

// ---------------- launcher ----------------
extern "C" void kernel_launch(void* const* d_in, const int* in_sizes, int n_in,
                              void* d_out, int out_size, void* d_ws, size_t ws_size,
                              hipStream_t stream) {
    (void)in_sizes; (void)n_in; (void)out_size;
    const float* hidden      = (const float*)d_in[0];
    const float* q_a_w       = (const float*)d_in[1];
    const float* q_a_ln_w    = (const float*)d_in[2];
    const float* q_b_w       = (const float*)d_in[3];
    const float* kv_a_w      = (const float*)d_in[4];
    const float* kv_a_ln_w   = (const float*)d_in[5];
    const float* kv_b_w      = (const float*)d_in[6];
    const float* o_w         = (const float*)d_in[7];
    const float* idx_wq_b_w  = (const float*)d_in[8];
    const float* idx_wk_w    = (const float*)d_in[9];
    const float* idx_kn_w    = (const float*)d_in[10];
    const float* idx_kn_b    = (const float*)d_in[11];
    const float* idx_wproj_w = (const float*)d_in[12];
    float* out = (float*)d_out;

    char* ws = (char*)d_ws;
    size_t off = 0;
    auto alloc = [&](size_t nbytes) -> void* {
        void* p = ws + off;
        off = (off + nbytes + 255) & ~(size_t)255;
        return p;
    };
    // persistent
    float* cos_t = (float*)alloc((size_t)SEQ * 32 * 4);
    float* sin_t = (float*)alloc((size_t)SEQ * 32 * 4);
    float* qbuf  = (float*)alloc((size_t)SEQ * 3072 * 4);
    float* ckv   = (float*)alloc((size_t)SEQ * 576 * 4);
    int*   sel   = (int*)alloc((size_t)SEQ * TOPK * 4);
    unsigned short* khg      = (unsigned short*)alloc((size_t)SEQ * 576 * 2);
    unsigned short* attno_bf = (unsigned short*)alloc((size_t)SEQ * 2048 * 2);
    unsigned short* qr_bf    = (unsigned short*)alloc((size_t)SEQ * QRANK * 2);
    unsigned short* q_b_bf   = (unsigned short*)alloc((size_t)3072 * QRANK * 2);
    unsigned short* kv_a_bf  = (unsigned short*)alloc((size_t)576 * HIDD * 2);
    unsigned short* o_w_bf   = (unsigned short*)alloc((size_t)HIDD * 2048 * 2);
    unsigned short* kv_b_bf  = (unsigned short*)alloc((size_t)4096 * 512 * 2);
    unsigned short* wkt      = (unsigned short*)alloc((size_t)16 * 512 * 128 * 2);
    size_t mark = off;
    // transients (dead after topk)
    float* qr    = (float*)alloc((size_t)SEQ * QRANK * 4);
    float* ccat  = (float*)alloc((size_t)SEQ * NCAT * 4);
    float* scores = (float*)alloc((size_t)SEQ * SEQ * 4);
    unsigned short* iqh = (unsigned short*)alloc((size_t)SEQ * 2048 * 2);
    unsigned short* iql = (unsigned short*)alloc((size_t)SEQ * 2048 * 2);
    unsigned short* ikh = (unsigned short*)alloc((size_t)SEQ * 128 * 2);
    unsigned short* ikl = (unsigned short*)alloc((size_t)SEQ * 128 * 2);
    // optional fast-path hi/lo precompute buffers (also transient)
    unsigned short* hidh  = (unsigned short*)alloc((size_t)HIDD * HIDD * 2);
    unsigned short* hidl  = (unsigned short*)alloc((size_t)HIDD * HIDD * 2);
    unsigned short* catwh = (unsigned short*)alloc((size_t)NCAT * HIDD * 2);
    unsigned short* catwl = (unsigned short*)alloc((size_t)NCAT * HIDD * 2);
    unsigned short* wqh   = (unsigned short*)alloc((size_t)HIDD * QRANK * 2);
    unsigned short* wql   = (unsigned short*)alloc((size_t)HIDD * QRANK * 2);
    unsigned short* qr_l  = (unsigned short*)alloc((size_t)SEQ * QRANK * 2);
    bool fast = (off <= ws_size);
    if (!fast) {
        hidh = hidl = catwh = catwl = wqh = wql = qr_l = nullptr;
    }
    // overlay region (alive after topk)
    off = mark;
    unsigned short* qabsb = (unsigned short*)alloc((size_t)SEQ * 16 * 512 * 2);
    unsigned short* ocomp = (unsigned short*)alloc((size_t)SEQ * 16 * 512 * 2);

    rope_table_kernel<<<dim3(SEQ), dim3(32), 0, stream>>>(cos_t, sin_t);

    // weight converts (single fused launch)
    cvt_bf16_4_kernel<<<2048, 256, 0, stream>>>(
        q_b_w, 3072 * QRANK / 4, kv_a_w, 576 * HIDD / 4,
        o_w, HIDD * 2048 / 4, kv_b_w, 4096 * 512 / 4,
        q_b_bf, kv_a_bf, o_w_bf, kv_b_bf);
    wkt_kernel<<<dim3(16, 4), 256, 0, stream>>>(kv_b_w, wkt);
    if (fast)
        cvt_split3_kernel<<<2048, 256, 0, stream>>>(
            hidden, q_a_w, idx_wk_w, idx_wproj_w, idx_wq_b_w,
            hidh, hidl, catwh, catwl, wqh, wql);

    // fused cat-GEMM: ccat = hidden @ [q_a_w; idx_wk_w; 0.25*idx_wproj_w]^T  (split-MFMA)
    gemm_cat_split_kernel<<<dim3(16, 14), 256, 0, stream>>>(
        hidden, q_a_w, idx_wk_w, idx_wproj_w, hidh, hidl, catwh, catwl, ccat);

    // qr = rmsnorm(ccat[:, :1536]) -> f32 + bf16 hi (+ lo if fast)
    rmsnorm_kernel<<<SEQ, 256, 0, stream>>>(ccat, q_a_ln_w, qr, qr_bf, qr_l, QRANK, NCAT);

    // ik = rope(layernorm(ccat[:, 1536:1664])) -> hi/lo split
    ln_rope_split_kernel<<<SEQ, 64, 0, stream>>>(ccat + 1536, NCAT, idx_kn_w, idx_kn_b, cos_t, sin_t, ikh, ikl);

    // q = qr @ q_b_w^T (bf16 MFMA, fused per-head RoPE on [128:192))
    mfma_nt_kernel<unsigned short, float><<<dim3(16, 24, 1), 256, 0, stream>>>(
        qr_bf, q_b_bf, qbuf, SEQ, 3072, QRANK, QRANK, QRANK, 3072, 0L, 0L, 0L,
        cos_t, sin_t, 1);

    // ckv = hidden @ kv_a_w^T (MFMA, fused kpe RoPE on [512:576)); fused rmsnorm+khg
    mfma_nt_kernel<float, float><<<dim3(16, 5, 1), 256, 0, stream>>>(
        hidden, kv_a_bf, ckv, SEQ, 576, HIDD, HIDD, HIDD, 576, 0L, 0L, 0L,
        cos_t, sin_t, 2);
    rmsnorm_khg_kernel<<<SEQ, 256, 0, stream>>>(ckv, kv_a_ln_w, khg);

    // iq = rope(qr @ idx_wq_b_w^T) -> hi/lo split (split-MFMA, fused epilogue)
    gemm_iq_split_kernel<<<dim3(16, 16), 256, 0, stream>>>(
        qr, idx_wq_b_w, qr_bf, qr_l, wqh, wql, cos_t, sin_t, iqh, iql);

    // indexer scores (split-MFMA, B-hoisted) + topk
    idx_scores_mfma_kernel<<<dim3(32, 32), 256, 0, stream>>>(iqh, iql, ikh, ikl, ccat + 1664, NCAT, scores);
    topk_kernel<<<SEQ, 1024, 0, stream>>>(scores, sel);

    // q absorption (bf16 MFMA, batched per head)
    mfma_nt_kernel<float, unsigned short><<<dim3(16, 4, 16), 256, 0, stream>>>(
        qbuf, wkt, qabsb, SEQ, 512, 128, 3072, 128, 16 * 512,
        192L, 512L * 128L, 512L, nullptr, nullptr, 0);

    // MFMA flash attention over selected keys -> ocomp (normalized bf16)
    attn_mfma_kernel<<<SEQ, 256, 0, stream>>>(qabsb, qbuf, khg, sel, ocomp);

    // output projection (bf16 MFMA, batched)
    mfma_nt_kernel<unsigned short, unsigned short><<<dim3(16, 1, 16), 256, 0, stream>>>(
        ocomp, kv_b_bf + (size_t)128 * 512, attno_bf, SEQ, 128, 512,
        16 * 512, 512, 2048, 512L, 256L * 512L, 128L, nullptr, nullptr, 0);

    // out = attno @ o_w^T (bf16 MFMA)
    mfma_nt_kernel<unsigned short, float><<<dim3(16, 16, 1), 256, 0, stream>>>(
        attno_bf, o_w_bf, out, SEQ, HIDD, 2048, 2048, 2048, HIDD, 0L, 0L, 0L,
        nullptr, nullptr, 0);
}

// Round 11
// 796.384 us; speedup vs baseline: 1.1099x; 1.1099x over previous
//
#include <hip/hip_runtime.h>
#include <hip/hip_bf16.h>
#include <math.h>

#define SEQ 2048
#define HIDD 2048
#define QRANK 1536
#define KVRANK 512
#define TOPK 512
#define EPSF 1e-6f
#define SCALE_ATTN 0.07216878364870323f  /* 192^-0.5 */
#define NCAT 1680

typedef __attribute__((ext_vector_type(8))) short short8v;
typedef __attribute__((ext_vector_type(4))) short short4v;
typedef __attribute__((ext_vector_type(4))) float f32x4;

__device__ inline unsigned short f2bf(float f) {
    unsigned u = __float_as_uint(f);
    unsigned r = (u + 0x7FFFu + ((u >> 16) & 1u)) >> 16;
    return (unsigned short)r;
}
__device__ inline float bf2f(unsigned short b) {
    return __uint_as_float(((unsigned)b) << 16);
}
__device__ inline void split2(float x, unsigned short& h, unsigned short& l) {
    h = f2bf(x);
    l = f2bf(x - bf2f(h));
}

// HW transpose read: 4 bf16 at p + j*32B (j=0..3).
__device__ inline short4v ds_read_tr16(const void* p) {
#if __has_builtin(__builtin_amdgcn_ds_read_tr16_b64)
    return __builtin_amdgcn_ds_read_tr16_b64((short4v*)p);
#else
    const unsigned short* u = (const unsigned short*)p;
    short4v r;
    r[0] = (short)u[0]; r[1] = (short)u[16]; r[2] = (short)u[32]; r[3] = (short)u[48];
    return r;
#endif
}

// ---------------- fused: RoPE table (blocks < SEQ) + f32->bf16 convert of 4 weight tensors ----------------
__global__ __launch_bounds__(256) void cvt_bf16_4_kernel(
    const float* __restrict__ a, int na4, const float* __restrict__ b, int nb4,
    const float* __restrict__ c, int nc4, const float* __restrict__ d, int nd4,
    unsigned short* __restrict__ oa, unsigned short* __restrict__ ob,
    unsigned short* __restrict__ oc, unsigned short* __restrict__ od,
    float* __restrict__ cos_t, float* __restrict__ sin_t)
{
    if (blockIdx.x < SEQ && threadIdx.x < 32) {
        int s = blockIdx.x, i = threadIdx.x;
        double inv = pow(10000.0, -((double)(2 * i)) / 64.0);
        double f = (double)s * inv;
        cos_t[s * 32 + i] = (float)cos(f);
        sin_t[s * 32 + i] = (float)sin(f);
    }
    int total = na4 + nb4 + nc4 + nd4;
    for (int i = blockIdx.x * 256 + threadIdx.x; i < total; i += gridDim.x * 256) {
        const float* src; unsigned short* dst; int j = i;
        if (j < na4) { src = a; dst = oa; }
        else if ((j -= na4) < nb4) { src = b; dst = ob; }
        else if ((j -= nb4) < nc4) { src = c; dst = oc; }
        else { j -= nc4; src = d; dst = od; }
        float4 v = ((const float4*)src)[j];
        ushort4 o;
        o.x = f2bf(v.x); o.y = f2bf(v.y); o.z = f2bf(v.z); o.w = f2bf(v.w);
        ((ushort4*)dst)[j] = o;
    }
}

// ---------------- hi/lo split precompute: hidden, cat-weights (with 0.25 tail), wq ----------------
__global__ __launch_bounds__(256) void cvt_split3_kernel(
    const float* __restrict__ hidden, const float* __restrict__ q_a_w,
    const float* __restrict__ idx_wk_w, const float* __restrict__ idx_wproj_w,
    const float* __restrict__ wq,
    unsigned short* __restrict__ hidh, unsigned short* __restrict__ hidl,
    unsigned short* __restrict__ catwh, unsigned short* __restrict__ catwl,
    unsigned short* __restrict__ wqh, unsigned short* __restrict__ wql)
{
    const int nhid4 = HIDD * HIDD / 4;
    const int ncat4 = NCAT * HIDD / 4;
    const int nwq4  = HIDD * QRANK / 4;
    int total = nhid4 + ncat4 + nwq4;
    for (int i = blockIdx.x * 256 + threadIdx.x; i < total; i += gridDim.x * 256) {
        int j = i;
        const float4* s4;
        unsigned short *dh, *dl;
        float scale = 1.f;
        if (j < nhid4) {
            s4 = (const float4*)hidden + j; dh = hidh; dl = hidl;
        } else if ((j -= nhid4) < ncat4) {
            int row = (j * 4) >> 11;  // /2048
            dh = catwh; dl = catwl;
            if (row < 1536) s4 = (const float4*)q_a_w + j;
            else if (row < 1664) s4 = (const float4*)idx_wk_w + (j - 1536 * 512);
            else { s4 = (const float4*)idx_wproj_w + (j - 1664 * 512); scale = 0.25f; }
        } else {
            j -= ncat4;
            s4 = (const float4*)wq + j; dh = wqh; dl = wql;
        }
        float4 v = *s4;
        float xs[4] = {v.x * scale, v.y * scale, v.z * scale, v.w * scale};
        ushort4 oh, ol;
        unsigned short h2, l2;
        split2(xs[0], h2, l2); oh.x = h2; ol.x = l2;
        split2(xs[1], h2, l2); oh.y = h2; ol.y = l2;
        split2(xs[2], h2, l2); oh.z = h2; ol.z = l2;
        split2(xs[3], h2, l2); oh.w = h2; ol.w = l2;
        ((ushort4*)dh)[j] = oh;
        ((ushort4*)dl)[j] = ol;
    }
}

// ---------------- wkt[h][n][d] = bf16(kv_b_w[h*256+d][n]), LDS-tiled transpose ----------------
__global__ __launch_bounds__(256) void wkt_kernel(const float* __restrict__ kvb,
                                                  unsigned short* __restrict__ wkt) {
    __shared__ float t[128][129];
    int h = blockIdx.x, n0 = blockIdx.y * 128;
    int tid = threadIdx.x;
    for (int it = tid; it < 128 * 32; it += 256) {
        int d = it >> 5, c4 = it & 31;
        float4 v = *(const float4*)(kvb + ((size_t)(h * 256 + d)) * 512 + n0 + c4 * 4);
        t[d][c4 * 4 + 0] = v.x; t[d][c4 * 4 + 1] = v.y;
        t[d][c4 * 4 + 2] = v.z; t[d][c4 * 4 + 3] = v.w;
    }
    __syncthreads();
    for (int it = tid; it < 128 * 32; it += 256) {
        int n = it >> 5, dc = it & 31;
        ushort4 o;
        o.x = f2bf(t[dc * 4 + 0][n]); o.y = f2bf(t[dc * 4 + 1][n]);
        o.z = f2bf(t[dc * 4 + 2][n]); o.w = f2bf(t[dc * 4 + 3][n]);
        *(ushort4*)(wkt + ((size_t)h * 512 + n0 + n) * 128 + dc * 4) = o;
    }
}

// ---------------- split-bf16 3-pass MFMA cat-GEMM (optional precomputed operands) ----------------
__global__ __launch_bounds__(256) void gemm_cat_split_kernel(
    const float* __restrict__ hidden, const float* __restrict__ q_a_w,
    const float* __restrict__ idx_wk_w, const float* __restrict__ idx_wproj_w,
    const unsigned short* __restrict__ hidh, const unsigned short* __restrict__ hidl,
    const unsigned short* __restrict__ catwh, const unsigned short* __restrict__ catwl,
    float* __restrict__ ccat)
{
    __shared__ __align__(16) unsigned short Ah[128 * 32], Al[128 * 32];
    __shared__ __align__(16) unsigned short Bh[128 * 32], Bl[128 * 32];
    int tid = threadIdx.x;
    int l = tid & 63, w = tid >> 6;
    int wr = w >> 1, wc = w & 1;
    int m0 = blockIdx.x * 128, n0 = blockIdx.y * 128;
    const bool pre = (hidh != nullptr);
    f32x4 acc[4][4] = {};
    for (int k0 = 0; k0 < HIDD; k0 += 32) {
        __syncthreads();
#pragma unroll
        for (int i = 0; i < 2; ++i) {
            int idx = tid + i * 256;
            int r = idx >> 2, cc = idx & 3;
            int sw = cc ^ (r & 3);
            int gb = n0 + r; if (gb > NCAT - 1) gb = NCAT - 1;
            if (pre) {
                size_t abase = (size_t)(m0 + r) * HIDD + k0 + cc * 8;
                *(short8v*)&Ah[r * 32 + sw * 8] = *(const short8v*)(hidh + abase);
                *(short8v*)&Al[r * 32 + sw * 8] = *(const short8v*)(hidl + abase);
                size_t bbase = (size_t)gb * HIDD + k0 + cc * 8;
                *(short8v*)&Bh[r * 32 + sw * 8] = *(const short8v*)(catwh + bbase);
                *(short8v*)&Bl[r * 32 + sw * 8] = *(const short8v*)(catwl + bbase);
            } else {
                {
                    const float* src = hidden + (size_t)(m0 + r) * HIDD + k0 + cc * 8;
                    float4 f0 = *(const float4*)src, f1 = *(const float4*)(src + 4);
                    float xs[8] = {f0.x, f0.y, f0.z, f0.w, f1.x, f1.y, f1.z, f1.w};
                    short8v dh, dl;
#pragma unroll
                    for (int e = 0; e < 8; ++e) {
                        unsigned short hh, ll; split2(xs[e], hh, ll);
                        dh[e] = (short)hh; dl[e] = (short)ll;
                    }
                    *(short8v*)&Ah[r * 32 + sw * 8] = dh;
                    *(short8v*)&Al[r * 32 + sw * 8] = dl;
                }
                {
                    float scale = 1.f;
                    const float* src;
                    if (gb < 1536) src = q_a_w + (size_t)gb * HIDD;
                    else if (gb < 1664) src = idx_wk_w + (size_t)(gb - 1536) * HIDD;
                    else { src = idx_wproj_w + (size_t)(gb - 1664) * HIDD; scale = 0.25f; }
                    src += k0 + cc * 8;
                    float4 f0 = *(const float4*)src, f1 = *(const float4*)(src + 4);
                    float xs[8] = {f0.x, f0.y, f0.z, f0.w, f1.x, f1.y, f1.z, f1.w};
                    short8v dh, dl;
#pragma unroll
                    for (int e = 0; e < 8; ++e) {
                        unsigned short hh, ll; split2(xs[e] * scale, hh, ll);
                        dh[e] = (short)hh; dl[e] = (short)ll;
                    }
                    *(short8v*)&Bh[r * 32 + sw * 8] = dh;
                    *(short8v*)&Bl[r * 32 + sw * 8] = dl;
                }
            }
        }
        __syncthreads();
        short8v avh[4], avl[4];
#pragma unroll
        for (int mt = 0; mt < 4; ++mt) {
            int row = wr * 64 + mt * 16 + (l & 15);
            int ch = (l >> 4) ^ (row & 3);
            avh[mt] = *(const short8v*)&Ah[row * 32 + ch * 8];
            avl[mt] = *(const short8v*)&Al[row * 32 + ch * 8];
        }
#pragma unroll
        for (int nt = 0; nt < 4; ++nt) {
            int row = wc * 64 + nt * 16 + (l & 15);
            int ch = (l >> 4) ^ (row & 3);
            short8v bvh = *(const short8v*)&Bh[row * 32 + ch * 8];
            short8v bvl = *(const short8v*)&Bl[row * 32 + ch * 8];
#pragma unroll
            for (int mt = 0; mt < 4; ++mt) {
                acc[mt][nt] = __builtin_amdgcn_mfma_f32_16x16x32_bf16(avh[mt], bvh, acc[mt][nt], 0, 0, 0);
                acc[mt][nt] = __builtin_amdgcn_mfma_f32_16x16x32_bf16(avh[mt], bvl, acc[mt][nt], 0, 0, 0);
                acc[mt][nt] = __builtin_amdgcn_mfma_f32_16x16x32_bf16(avl[mt], bvh, acc[mt][nt], 0, 0, 0);
            }
        }
    }
#pragma unroll
    for (int mt = 0; mt < 4; ++mt)
#pragma unroll
        for (int nt = 0; nt < 4; ++nt)
#pragma unroll
            for (int i = 0; i < 4; ++i) {
                int gm = m0 + wr * 64 + mt * 16 + (l >> 4) * 4 + i;
                int gn = n0 + wc * 64 + nt * 16 + (l & 15);
                if (gn < NCAT) ccat[(size_t)gm * NCAT + gn] = acc[mt][nt][i];
            }
}

// ---------------- split-bf16 3-pass MFMA iq-GEMM, fused RoPE + hi/lo split output ----------------
__global__ __launch_bounds__(256) void gemm_iq_split_kernel(
    const float* __restrict__ qr, const float* __restrict__ wq,
    const unsigned short* __restrict__ qrh, const unsigned short* __restrict__ qrl,
    const unsigned short* __restrict__ wqh, const unsigned short* __restrict__ wql,
    const float* __restrict__ cos_t, const float* __restrict__ sin_t,
    unsigned short* __restrict__ iqh, unsigned short* __restrict__ iql)
{
    __shared__ __align__(16) unsigned short Ah[128 * 32], Al[128 * 32];
    __shared__ __align__(16) unsigned short Bh[128 * 32], Bl[128 * 32];
    int tid = threadIdx.x;
    int l = tid & 63, w = tid >> 6;
    int wr = w >> 1, wc = w & 1;
    int m0 = blockIdx.x * 128, n0 = blockIdx.y * 128;
    int hh_ = blockIdx.y;  // head
    const bool pre = (wqh != nullptr);
    f32x4 acc[4][4] = {};
    for (int k0 = 0; k0 < QRANK; k0 += 32) {
        __syncthreads();
#pragma unroll
        for (int i = 0; i < 2; ++i) {
            int idx = tid + i * 256;
            int r = idx >> 2, cc = idx & 3;
            int sw = cc ^ (r & 3);
            if (pre) {
                size_t abase = (size_t)(m0 + r) * QRANK + k0 + cc * 8;
                *(short8v*)&Ah[r * 32 + sw * 8] = *(const short8v*)(qrh + abase);
                *(short8v*)&Al[r * 32 + sw * 8] = *(const short8v*)(qrl + abase);
                size_t bbase = (size_t)(n0 + r) * QRANK + k0 + cc * 8;
                *(short8v*)&Bh[r * 32 + sw * 8] = *(const short8v*)(wqh + bbase);
                *(short8v*)&Bl[r * 32 + sw * 8] = *(const short8v*)(wql + bbase);
            } else {
                {
                    const float* src = qr + (size_t)(m0 + r) * QRANK + k0 + cc * 8;
                    float4 f0 = *(const float4*)src, f1 = *(const float4*)(src + 4);
                    float xs[8] = {f0.x, f0.y, f0.z, f0.w, f1.x, f1.y, f1.z, f1.w};
                    short8v dh, dl;
#pragma unroll
                    for (int e = 0; e < 8; ++e) {
                        unsigned short h2, l2; split2(xs[e], h2, l2);
                        dh[e] = (short)h2; dl[e] = (short)l2;
                    }
                    *(short8v*)&Ah[r * 32 + sw * 8] = dh;
                    *(short8v*)&Al[r * 32 + sw * 8] = dl;
                }
                {
                    const float* src = wq + (size_t)(n0 + r) * QRANK + k0 + cc * 8;
                    float4 f0 = *(const float4*)src, f1 = *(const float4*)(src + 4);
                    float xs[8] = {f0.x, f0.y, f0.z, f0.w, f1.x, f1.y, f1.z, f1.w};
                    short8v dh, dl;
#pragma unroll
                    for (int e = 0; e < 8; ++e) {
                        unsigned short h2, l2; split2(xs[e], h2, l2);
                        dh[e] = (short)h2; dl[e] = (short)l2;
                    }
                    *(short8v*)&Bh[r * 32 + sw * 8] = dh;
                    *(short8v*)&Bl[r * 32 + sw * 8] = dl;
                }
            }
        }
        __syncthreads();
        short8v avh[4], avl[4];
#pragma unroll
        for (int mt = 0; mt < 4; ++mt) {
            int row = wr * 64 + mt * 16 + (l & 15);
            int ch = (l >> 4) ^ (row & 3);
            avh[mt] = *(const short8v*)&Ah[row * 32 + ch * 8];
            avl[mt] = *(const short8v*)&Al[row * 32 + ch * 8];
        }
#pragma unroll
        for (int nt = 0; nt < 4; ++nt) {
            int row = wc * 64 + nt * 16 + (l & 15);
            int ch = (l >> 4) ^ (row & 3);
            short8v bvh = *(const short8v*)&Bh[row * 32 + ch * 8];
            short8v bvl = *(const short8v*)&Bl[row * 32 + ch * 8];
#pragma unroll
            for (int mt = 0; mt < 4; ++mt) {
                acc[mt][nt] = __builtin_amdgcn_mfma_f32_16x16x32_bf16(avh[mt], bvh, acc[mt][nt], 0, 0, 0);
                acc[mt][nt] = __builtin_amdgcn_mfma_f32_16x16x32_bf16(avh[mt], bvl, acc[mt][nt], 0, 0, 0);
                acc[mt][nt] = __builtin_amdgcn_mfma_f32_16x16x32_bf16(avl[mt], bvh, acc[mt][nt], 0, 0, 0);
            }
        }
    }
    if (wc == 0) {
#pragma unroll
        for (int mt = 0; mt < 4; ++mt)
#pragma unroll
            for (int nt = 0; nt < 2; ++nt)
#pragma unroll
                for (int i = 0; i < 4; ++i) {
                    int q = m0 + wr * 64 + mt * 16 + (l >> 4) * 4 + i;
                    int dd = nt * 16 + (l & 15);
                    float c = cos_t[q * 32 + dd], s = sin_t[q * 32 + dd];
                    float x1 = acc[mt][nt][i], x2 = acc[mt][nt + 2][i];
                    acc[mt][nt][i] = x1 * c - x2 * s;
                    acc[mt][nt + 2][i] = x2 * c + x1 * s;
                }
    }
#pragma unroll
    for (int mt = 0; mt < 4; ++mt)
#pragma unroll
        for (int nt = 0; nt < 4; ++nt)
#pragma unroll
            for (int i = 0; i < 4; ++i) {
                int q = m0 + wr * 64 + mt * 16 + (l >> 4) * 4 + i;
                int d = wc * 64 + nt * 16 + (l & 15);
                size_t idx = ((size_t)q * 16 + hh_) * 128 + d;
                unsigned short h2, l2; split2(acc[mt][nt][i], h2, l2);
                iqh[idx] = h2; iql[idx] = l2;
            }
}

// ---------------- bf16 MFMA NT GEMM, batched, optional fused RoPE epilogue ----------------
template <typename TA, typename TC>
__global__ __launch_bounds__(256) void mfma_nt_kernel(
    const TA* __restrict__ A, const unsigned short* __restrict__ B, TC* __restrict__ C,
    int M, int N, int K, int lda, int ldb, int ldc, long ab, long bb, long cb,
    const float* __restrict__ cos_t, const float* __restrict__ sin_t, int rope_mode)
{
    __shared__ __align__(16) unsigned short Asl[128 * 32];
    __shared__ __align__(16) unsigned short Bsl[128 * 32];
    int z = blockIdx.z;
    const TA* Az = A + (size_t)z * ab;
    const unsigned short* Bz = B + (size_t)z * bb;
    TC* Cz = C + (size_t)z * cb;
    int tid = threadIdx.x;
    int l = tid & 63, w = tid >> 6;
    int wr = w >> 1, wc = w & 1;
    int m0 = blockIdx.x * 128, n0 = blockIdx.y * 128;
    f32x4 acc[4][4] = {};

    for (int k0 = 0; k0 < K; k0 += 32) {
        __syncthreads();
#pragma unroll
        for (int i = 0; i < 2; ++i) {
            int idx = tid + i * 256;
            int r = idx >> 2, cc = idx & 3;
            int sw = cc ^ (r & 3);
            {
                short8v d;
                const TA* src = Az + (size_t)(m0 + r) * lda + k0 + cc * 8;
                if constexpr (sizeof(TA) == 2) {
                    d = *(const short8v*)src;
                } else {
                    float4 f0 = *(const float4*)src;
                    float4 f1 = *(const float4*)(src + 4);
                    d[0] = (short)f2bf(f0.x); d[1] = (short)f2bf(f0.y);
                    d[2] = (short)f2bf(f0.z); d[3] = (short)f2bf(f0.w);
                    d[4] = (short)f2bf(f1.x); d[5] = (short)f2bf(f1.y);
                    d[6] = (short)f2bf(f1.z); d[7] = (short)f2bf(f1.w);
                }
                *(short8v*)&Asl[r * 32 + sw * 8] = d;
            }
            {
                int gb = n0 + r; if (gb > N - 1) gb = N - 1;
                short8v d = *(const short8v*)(Bz + (size_t)gb * ldb + k0 + cc * 8);
                *(short8v*)&Bsl[r * 32 + sw * 8] = d;
            }
        }
        __syncthreads();
        short8v av[4], bv[4];
#pragma unroll
        for (int mt = 0; mt < 4; ++mt) {
            int row = wr * 64 + mt * 16 + (l & 15);
            int ch = (l >> 4) ^ (row & 3);
            av[mt] = *(const short8v*)&Asl[row * 32 + ch * 8];
        }
#pragma unroll
        for (int nt = 0; nt < 4; ++nt) {
            int row = wc * 64 + nt * 16 + (l & 15);
            int ch = (l >> 4) ^ (row & 3);
            bv[nt] = *(const short8v*)&Bsl[row * 32 + ch * 8];
        }
#pragma unroll
        for (int mt = 0; mt < 4; ++mt)
#pragma unroll
            for (int nt = 0; nt < 4; ++nt)
                acc[mt][nt] = __builtin_amdgcn_mfma_f32_16x16x32_bf16(av[mt], bv[nt], acc[mt][nt], 0, 0, 0);
    }
    if (rope_mode) {
        int gcol64 = (n0 >> 6) + wc;
        bool dorope = (rope_mode == 1) ? ((gcol64 % 3) == 2) : (gcol64 == 8);
        if (dorope) {
#pragma unroll
            for (int mt = 0; mt < 4; ++mt)
#pragma unroll
                for (int nt = 0; nt < 2; ++nt)
#pragma unroll
                    for (int i = 0; i < 4; ++i) {
                        int q = m0 + wr * 64 + mt * 16 + (l >> 4) * 4 + i;
                        int dd = nt * 16 + (l & 15);
                        float c = cos_t[q * 32 + dd], sn = sin_t[q * 32 + dd];
                        float x1 = acc[mt][nt][i], x2 = acc[mt][nt + 2][i];
                        acc[mt][nt][i] = x1 * c - x2 * sn;
                        acc[mt][nt + 2][i] = x2 * c + x1 * sn;
                    }
        }
    }
#pragma unroll
    for (int mt = 0; mt < 4; ++mt) {
#pragma unroll
        for (int nt = 0; nt < 4; ++nt) {
#pragma unroll
            for (int i = 0; i < 4; ++i) {
                int gm = m0 + wr * 64 + mt * 16 + (l >> 4) * 4 + i;
                int gn = n0 + wc * 64 + nt * 16 + (l & 15);
                if (gn < N) {
                    float v = acc[mt][nt][i];
                    if constexpr (sizeof(TC) == 4) Cz[(size_t)gm * ldc + gn] = v;
                    else Cz[(size_t)gm * ldc + gn] = f2bf(v);
                }
            }
        }
    }
}

// ---------------- RMSNorm (qr path), bf16 hi + optional lo outputs ----------------
__global__ __launch_bounds__(256) void rmsnorm_kernel(
    const float* __restrict__ in, const float* __restrict__ w, float* __restrict__ out,
    unsigned short* __restrict__ bf_out, unsigned short* __restrict__ bf_lo,
    int n, int in_stride)
{
    int row = blockIdx.x, tid = threadIdx.x;
    const float* x = in + (size_t)row * in_stride;
    float4 v[2];
    int cnt = 0;
    float ss = 0.f;
    int nf4 = n >> 2;
    for (int i = tid; i < nf4; i += 256) {
        float4 t = *(const float4*)(x + i * 4);
        v[cnt++] = t;
        ss += t.x * t.x + t.y * t.y + t.z * t.z + t.w * t.w;
    }
#pragma unroll
    for (int m = 32; m; m >>= 1) ss += __shfl_xor(ss, m);
    __shared__ float red[8];
    int wid = tid >> 6;
    if ((tid & 63) == 0) red[wid] = ss;
    __syncthreads();
    if (tid == 0) {
        float s = red[0] + red[1] + red[2] + red[3];
        red[4] = rsqrtf(s / (float)n + EPSF);
    }
    __syncthreads();
    float scale = red[4];
    cnt = 0;
    for (int i = tid; i < nf4; i += 256) {
        float4 t = v[cnt++];
        float4 wv = *(const float4*)(w + i * 4);
        float4 o;
        o.x = t.x * scale * wv.x; o.y = t.y * scale * wv.y;
        o.z = t.z * scale * wv.z; o.w = t.w * scale * wv.w;
        *(float4*)(out + (size_t)row * n + i * 4) = o;
        if (bf_out) {
            ushort4 ob;
            ob.x = f2bf(o.x); ob.y = f2bf(o.y); ob.z = f2bf(o.z); ob.w = f2bf(o.w);
            *(ushort4*)(bf_out + (size_t)row * n + i * 4) = ob;
            if (bf_lo) {
                ushort4 ol;
                ol.x = f2bf(o.x - bf2f(ob.x)); ol.y = f2bf(o.y - bf2f(ob.y));
                ol.z = f2bf(o.z - bf2f(ob.z)); ol.w = f2bf(o.w - bf2f(ob.w));
                *(ushort4*)(bf_lo + (size_t)row * n + i * 4) = ol;
            }
        }
    }
}

// ---------------- fused RMSNorm(ckv[:512]) -> khg[0:512] bf16, + kpe copy -> khg[512:576] ----------------
__global__ __launch_bounds__(256) void rmsnorm_khg_kernel(
    const float* __restrict__ ckv, const float* __restrict__ w,
    unsigned short* __restrict__ khg)
{
    int row = blockIdx.x, tid = threadIdx.x;
    const float* x = ckv + (size_t)row * 576;
    float4 v = make_float4(0.f, 0.f, 0.f, 0.f);
    float ss = 0.f;
    if (tid < 128) {
        v = *(const float4*)(x + tid * 4);
        ss = v.x * v.x + v.y * v.y + v.z * v.z + v.w * v.w;
    }
#pragma unroll
    for (int mm = 32; mm; mm >>= 1) ss += __shfl_xor(ss, mm);
    __shared__ float red[8];
    if ((tid & 63) == 0) red[tid >> 6] = ss;
    __syncthreads();
    if (tid == 0) red[4] = rsqrtf((red[0] + red[1] + red[2] + red[3]) * (1.f / 512.f) + EPSF);
    __syncthreads();
    float scale = red[4];
    if (tid < 128) {
        float4 wv = *(const float4*)(w + tid * 4);
        ushort4 ob;
        ob.x = f2bf(v.x * scale * wv.x); ob.y = f2bf(v.y * scale * wv.y);
        ob.z = f2bf(v.z * scale * wv.z); ob.w = f2bf(v.w * scale * wv.w);
        *(ushort4*)(khg + (size_t)row * 576 + tid * 4) = ob;
    } else if (tid < 192) {
        khg[(size_t)row * 576 + 512 + (tid - 128)] = f2bf(x[512 + tid - 128]);
    }
}

// ---------------- LayerNorm + RoPE + hi/lo split for ik ----------------
__global__ __launch_bounds__(64) void ln_rope_split_kernel(
    const float* __restrict__ in, int stride,
    const float* __restrict__ w, const float* __restrict__ b,
    const float* __restrict__ cos_t, const float* __restrict__ sin_t,
    unsigned short* __restrict__ ikh, unsigned short* __restrict__ ikl)
{
    int row = blockIdx.x, tid = threadIdx.x;
    const float* x = in + (size_t)row * stride;
    float x0 = x[tid], x1 = x[tid + 64];
    float s = x0 + x1, ss = x0 * x0 + x1 * x1;
#pragma unroll
    for (int m = 32; m; m >>= 1) { s += __shfl_xor(s, m); ss += __shfl_xor(ss, m); }
    float mean = s * (1.f / 128.f);
    float var = ss * (1.f / 128.f) - mean * mean;
    float r = rsqrtf(var + EPSF);
    float n0 = (x0 - mean) * r * w[tid] + b[tid];
    float n1 = (x1 - mean) * r * w[tid + 64] + b[tid + 64];
    float c = cos_t[row * 32 + (tid & 31)], sn = sin_t[row * 32 + (tid & 31)];
    float other = __shfl_xor(n0, 32);
    float r0 = (tid < 32) ? (n0 * c - other * sn) : (n0 * c + other * sn);
    unsigned short h2, l2;
    split2(r0, h2, l2);
    ikh[(size_t)row * 128 + tid] = h2; ikl[(size_t)row * 128 + tid] = l2;
    split2(n1, h2, l2);
    ikh[(size_t)row * 128 + 64 + tid] = h2; ikl[(size_t)row * 128 + 64 + tid] = l2;
}

// ---------------- indexer scores via split-bf16 3-pass MFMA (B-frags hoisted to regs) ----------------
__global__ __launch_bounds__(256) void idx_scores_mfma_kernel(
    const unsigned short* __restrict__ iqh, const unsigned short* __restrict__ iql,
    const unsigned short* __restrict__ ikh, const unsigned short* __restrict__ ikl,
    const float* __restrict__ iwsrc, int iw_stride,
    float* __restrict__ scores)
{
    int q0 = blockIdx.x * 64, k0 = blockIdx.y * 64;
    int tid = threadIdx.x;
    if (k0 > q0 + 63) {
        for (int t = tid; t < 64 * 64; t += 256) {
            int r = t >> 6, c = t & 63;
            scores[(size_t)(q0 + r) * SEQ + k0 + c] = -INFINITY;
        }
        return;
    }
    __shared__ __align__(16) unsigned short skh[64 * 128], skl[64 * 128];
    __shared__ __align__(16) unsigned short sqh[64 * 128], sql[64 * 128];
    __shared__ float iws[64][16];
    int l = tid & 63, w = tid >> 6;
    for (int it = tid; it < 64 * 16; it += 256) {
        int r = it >> 4, c = it & 15;
        int sw = c ^ (r & 15);
        *(short8v*)&skh[r * 128 + sw * 8] = *(const short8v*)(ikh + (size_t)(k0 + r) * 128 + c * 8);
        *(short8v*)&skl[r * 128 + sw * 8] = *(const short8v*)(ikl + (size_t)(k0 + r) * 128 + c * 8);
    }
    {
        int r = tid >> 2, c = tid & 3;
        *(float4*)&iws[r][c * 4] = *(const float4*)(iwsrc + (size_t)(q0 + r) * iw_stride + c * 4);
    }
    __syncthreads();
    short8v bhr[4][4], blr[4][4];  // [nt][ks]
#pragma unroll
    for (int nt = 0; nt < 4; ++nt)
#pragma unroll
        for (int ks = 0; ks < 4; ++ks) {
            int brow = nt * 16 + (l & 15);
            int bch = ((l >> 4) + ks * 4) ^ (brow & 15);
            bhr[nt][ks] = *(const short8v*)&skh[brow * 128 + bch * 8];
            blr[nt][ks] = *(const short8v*)&skl[brow * 128 + bch * 8];
        }
    f32x4 acc[4] = {};
    for (int h = 0; h < 16; ++h) {
        __syncthreads();
        for (int it = tid; it < 64 * 16; it += 256) {
            int r = it >> 4, c = it & 15;
            int sw = c ^ (r & 15);
            size_t base = ((size_t)(q0 + r) * 16 + h) * 128 + c * 8;
            *(short8v*)&sqh[r * 128 + sw * 8] = *(const short8v*)(iqh + base);
            *(short8v*)&sql[r * 128 + sw * 8] = *(const short8v*)(iql + base);
        }
        __syncthreads();
        f32x4 dot[4] = {};
#pragma unroll
        for (int ks = 0; ks < 4; ++ks) {
            int arow = w * 16 + (l & 15);
            int ach = ((l >> 4) + ks * 4) ^ (arow & 15);
            short8v ah = *(const short8v*)&sqh[arow * 128 + ach * 8];
            short8v al = *(const short8v*)&sql[arow * 128 + ach * 8];
#pragma unroll
            for (int nt = 0; nt < 4; ++nt) {
                dot[nt] = __builtin_amdgcn_mfma_f32_16x16x32_bf16(ah, bhr[nt][ks], dot[nt], 0, 0, 0);
                dot[nt] = __builtin_amdgcn_mfma_f32_16x16x32_bf16(ah, blr[nt][ks], dot[nt], 0, 0, 0);
                dot[nt] = __builtin_amdgcn_mfma_f32_16x16x32_bf16(al, bhr[nt][ks], dot[nt], 0, 0, 0);
            }
        }
#pragma unroll
        for (int nt = 0; nt < 4; ++nt)
#pragma unroll
            for (int i = 0; i < 4; ++i) {
                float wv = iws[w * 16 + (l >> 4) * 4 + i][h];
                acc[nt][i] += wv * fmaxf(dot[nt][i], 0.f);
            }
    }
#pragma unroll
    for (int nt = 0; nt < 4; ++nt)
#pragma unroll
        for (int i = 0; i < 4; ++i) {
            int q = q0 + w * 16 + (l >> 4) * 4 + i;
            int k = k0 + nt * 16 + (l & 15);
            scores[(size_t)q * SEQ + k] = (k <= q) ? acc[nt][i] : -INFINITY;
        }
}

// ---------------- top-512 per row via bitonic sort ----------------
__global__ __launch_bounds__(1024) void topk_kernel(
    const float* __restrict__ scores, int* __restrict__ sel)
{
    int qi = blockIdx.x, tid = threadIdx.x;
    __shared__ unsigned long long keys[2048];
    const float* srow = scores + (size_t)qi * SEQ;
#pragma unroll
    for (int r = 0; r < 2; ++r) {
        int k = tid + r * 1024;
        unsigned u = __float_as_uint(srow[k]);
        unsigned mv = (u & 0x80000000u) ? ~u : (u | 0x80000000u);
        keys[k] = ((unsigned long long)mv << 32) | (unsigned)(2047 - k);
    }
    for (int ksz = 2; ksz <= 2048; ksz <<= 1) {
        for (int j = ksz >> 1; j > 0; j >>= 1) {
            __syncthreads();
#pragma unroll 1
            for (int r = 0; r < 2; ++r) {
                int i = tid + r * 1024;
                int ixj = i ^ j;
                if (ixj > i) {
                    unsigned long long a = keys[i], b = keys[ixj];
                    bool dir = ((i & ksz) == 0);
                    if ((a < b) == dir) { keys[i] = b; keys[ixj] = a; }
                }
            }
        }
    }
    __syncthreads();
    if (tid < TOPK) {
        int k = 2047 - (int)(keys[tid] & 0xFFFFFFFFu);
        sel[(size_t)qi * TOPK + tid] = (tid <= qi) ? k : -1;
    }
}

// ---------------- MFMA flash attention: 64-key tiles, tr_b16 PV, direct staging (round-9 structure) ----------------
// LDS layout:
//   [0, 66560)       : V subtiled [32 dblocks][64 keys][16 d] bf16, dblock stride 2080B (+32B pad)
//   [66560, 74752)   : kpe row-major [64][64] bf16, XOR-swizzled byte^((key&7)<<4)
//   [74752, 76800)   : plds [64 keys][16 heads] bf16
//   [76800, 77312)   : smax[4][16], ssum[4][16]
__global__ __launch_bounds__(256) void attn_mfma_kernel(
    const unsigned short* __restrict__ qabs,  // (S,16,512) bf16
    const float* __restrict__ qsrc,           // qbuf (S,16,192) f32, qpe at +128
    const unsigned short* __restrict__ khg,   // (S,576) bf16: [ckvn|kpe]
    const int* __restrict__ sel,              // (S,512)
    unsigned short* __restrict__ ocomp)       // (S,16,512) bf16 normalized
{
    __shared__ __align__(16) char smem[77312];
    unsigned short* plds = (unsigned short*)(smem + 74752);
    float* smax = (float*)(smem + 76800);   // [4][16]
    float* ssum = (float*)(smem + 77056);   // [4][16]

    const int qi = blockIdx.x;
    const int tid = threadIdx.x;
    const int l = tid & 63, w = tid >> 6;
    const int lg = l >> 4, lr = l & 15;
    const int nv = min(TOPK, qi + 1);
    const int ntile = (nv + 63) >> 6;
    const int krow = w * 16 + lr;

    // static per-thread staging roles (wave-coalesced: wave w stages keys w+4j, contiguous 1KB per instr)
    const int ck = tid >> 6, cc = tid & 63;   // ckvn: chunk cc of keys ck+4j (j=0..15)
    const int pk = tid >> 3, pc = tid & 7;    // kpe:  chunk pc of keys pk+32j (j=0..1)
    const int* selrow = sel + (size_t)qi * TOPK;

    // A-fragments: head = lr, k-dims lg*8 + ks*32
    short8v aq[18];
    {
        const unsigned short* qa = qabs + ((size_t)qi * 16 + lr) * 512 + lg * 8;
#pragma unroll
        for (int ks = 0; ks < 16; ++ks)
            aq[ks] = *(const short8v*)(qa + ks * 32);
        const float* qp = qsrc + (size_t)qi * 3072 + lr * 192 + 128 + lg * 8;
#pragma unroll
        for (int ks = 0; ks < 2; ++ks) {
            float4 f0 = *(const float4*)(qp + ks * 32);
            float4 f1 = *(const float4*)(qp + ks * 32 + 4);
            short8v d;
            d[0] = (short)f2bf(f0.x); d[1] = (short)f2bf(f0.y);
            d[2] = (short)f2bf(f0.z); d[3] = (short)f2bf(f0.w);
            d[4] = (short)f2bf(f1.x); d[5] = (short)f2bf(f1.y);
            d[6] = (short)f2bf(f1.z); d[7] = (short)f2bf(f1.w);
            aq[16 + ks] = d;
        }
    }

    // byte base for score-phase V reads: key=krow, dblock=(lg>>1), 16B half=(lg&1)
    const int sbase = krow * 32 + (lg >> 1) * 2080 + (lg & 1) * 16;
    // byte base for tr_b16 PV reads: dblock = w*8 (+nt), key0 = lg*8 (+kb*32), col = lr
    const int vboff = w * 16640 + lg * 256 + lr * 2;

    float m[4] = {-1e30f, -1e30f, -1e30f, -1e30f};
    float lsum[4] = {0.f, 0.f, 0.f, 0.f};
    f32x4 oacc[8] = {};

    for (int t = 0; t < ntile; ++t) {
        const int j0 = t * 64;
        __syncthreads();   // previous tile's LDS reads complete
        // direct global->LDS staging (per-thread sel read; no selb broadcast)
#pragma unroll
        for (int j = 0; j < 16; ++j) {
            int sv = selrow[j0 + ck + 4 * j];
            if (sv < 0) sv = 0;
            short8v v = *(const short8v*)(khg + (size_t)sv * 576 + cc * 8);
            *(short8v*)(smem + (cc >> 1) * 2080 + (ck + 4 * j) * 32 + (cc & 1) * 16) = v;
        }
#pragma unroll
        for (int j = 0; j < 2; ++j) {
            int sv = selrow[j0 + pk + 32 * j];
            if (sv < 0) sv = 0;
            short8v v = *(const short8v*)(khg + (size_t)sv * 576 + 512 + pc * 8);
            int key = pk + 32 * j;
            *(short8v*)(smem + 66560 + ((key * 128 + pc * 16) ^ ((key & 7) << 4))) = v;
        }
        __syncthreads();
        // scores for wave's 16 keys
        f32x4 s = {};
#pragma unroll
        for (int ks = 0; ks < 16; ++ks) {
            short8v b = *(const short8v*)(smem + sbase + ks * 4160);
            s = __builtin_amdgcn_mfma_f32_16x16x32_bf16(aq[ks], b, s, 0, 0, 0);
        }
#pragma unroll
        for (int ks = 0; ks < 2; ++ks) {
            short8v b = *(const short8v*)(smem + 66560 +
                ((krow * 128 + ks * 64 + lg * 16) ^ ((krow & 7) << 4)));
            s = __builtin_amdgcn_mfma_f32_16x16x32_bf16(aq[16 + ks], b, s, 0, 0, 0);
        }
        bool kvalid = (j0 + krow) < nv;
#pragma unroll
        for (int i = 0; i < 4; ++i)
            s[i] = kvalid ? s[i] * SCALE_ATTN : -1e30f;
        float tm[4];
#pragma unroll
        for (int i = 0; i < 4; ++i) tm[i] = s[i];
#pragma unroll
        for (int sh = 1; sh < 16; sh <<= 1)
#pragma unroll
            for (int i = 0; i < 4; ++i) tm[i] = fmaxf(tm[i], __shfl_xor(tm[i], sh));
        if (lr == 0) *(float4*)&smax[w * 16 + lg * 4] = make_float4(tm[0], tm[1], tm[2], tm[3]);
        __syncthreads();
        float mn[4], scl[4];
#pragma unroll
        for (int i = 0; i < 4; ++i) {
            int h = lg * 4 + i;
            float tmax = fmaxf(fmaxf(smax[h], smax[16 + h]), fmaxf(smax[32 + h], smax[48 + h]));
            mn[i] = fmaxf(m[i], tmax);
            scl[i] = __expf(m[i] - mn[i]);
            m[i] = mn[i];
        }
        float p[4], rs[4];
#pragma unroll
        for (int i = 0; i < 4; ++i) { p[i] = __expf(s[i] - mn[i]); rs[i] = p[i]; }
#pragma unroll
        for (int sh = 1; sh < 16; sh <<= 1)
#pragma unroll
            for (int i = 0; i < 4; ++i) rs[i] += __shfl_xor(rs[i], sh);
        if (lr == 0) *(float4*)&ssum[w * 16 + lg * 4] = make_float4(rs[0], rs[1], rs[2], rs[3]);
        {
            ushort4 pb;
            pb.x = f2bf(p[0]); pb.y = f2bf(p[1]); pb.z = f2bf(p[2]); pb.w = f2bf(p[3]);
            *(ushort4*)&plds[(w * 16 + lr) * 16 + lg * 4] = pb;
        }
        __syncthreads();
#pragma unroll
        for (int i = 0; i < 4; ++i) {
            int h = lg * 4 + i;
            float ts = ssum[h] + ssum[16 + h] + ssum[32 + h] + ssum[48 + h];
            lsum[i] = lsum[i] * scl[i] + ts;
        }
#pragma unroll
        for (int nt = 0; nt < 8; ++nt)
#pragma unroll
            for (int i = 0; i < 4; ++i) oacc[nt][i] *= scl[i];
        // PV: wave handles dims [w*128, w*128+128); B-frags via ds_read_tr16 (HW transpose)
#pragma unroll
        for (int kb = 0; kb < 2; ++kb) {
            short8v af;
#pragma unroll
            for (int j = 0; j < 8; ++j)
                af[j] = (short)plds[(kb * 32 + lg * 8 + j) * 16 + lr];
#pragma unroll
            for (int nt = 0; nt < 8; ++nt) {
                const char* a = smem + vboff + kb * 1024 + nt * 2080;
                short4v t0 = ds_read_tr16(a);          // keys +0..3  (elem j at +32B)
                short4v t1 = ds_read_tr16(a + 128);    // keys +4..7
                short8v bf = __builtin_shufflevector(t0, t1, 0, 1, 2, 3, 4, 5, 6, 7);
                oacc[nt] = __builtin_amdgcn_mfma_f32_16x16x32_bf16(af, bf, oacc[nt], 0, 0, 0);
            }
        }
    }
    float inv[4];
#pragma unroll
    for (int i = 0; i < 4; ++i) inv[i] = 1.f / lsum[i];
    unsigned short* ob = ocomp + (size_t)qi * 16 * 512;
#pragma unroll
    for (int nt = 0; nt < 8; ++nt) {
        int d = w * 128 + nt * 16 + lr;
#pragma unroll
        for (int i = 0; i < 4; ++i) {
            int h = lg * 4 + i;
            ob[h * 512 + d] = f2bf(oacc[nt][i] * inv[i]);
        }
    }
}

// ---------------- launcher ----------------
extern "C" void kernel_launch(void* const* d_in, const int* in_sizes, int n_in,
                              void* d_out, int out_size, void* d_ws, size_t ws_size,
                              hipStream_t stream) {
    (void)in_sizes; (void)n_in; (void)out_size;
    const float* hidden      = (const float*)d_in[0];
    const float* q_a_w       = (const float*)d_in[1];
    const float* q_a_ln_w    = (const float*)d_in[2];
    const float* q_b_w       = (const float*)d_in[3];
    const float* kv_a_w      = (const float*)d_in[4];
    const float* kv_a_ln_w   = (const float*)d_in[5];
    const float* kv_b_w      = (const float*)d_in[6];
    const float* o_w         = (const float*)d_in[7];
    const float* idx_wq_b_w  = (const float*)d_in[8];
    const float* idx_wk_w    = (const float*)d_in[9];
    const float* idx_kn_w    = (const float*)d_in[10];
    const float* idx_kn_b    = (const float*)d_in[11];
    const float* idx_wproj_w = (const float*)d_in[12];
    float* out = (float*)d_out;

    char* ws = (char*)d_ws;
    size_t off = 0;
    auto alloc = [&](size_t nbytes) -> void* {
        void* p = ws + off;
        off = (off + nbytes + 255) & ~(size_t)255;
        return p;
    };
    // persistent
    float* cos_t = (float*)alloc((size_t)SEQ * 32 * 4);
    float* sin_t = (float*)alloc((size_t)SEQ * 32 * 4);
    float* qbuf  = (float*)alloc((size_t)SEQ * 3072 * 4);
    float* ckv   = (float*)alloc((size_t)SEQ * 576 * 4);
    int*   sel   = (int*)alloc((size_t)SEQ * TOPK * 4);
    unsigned short* khg      = (unsigned short*)alloc((size_t)SEQ * 576 * 2);
    unsigned short* attno_bf = (unsigned short*)alloc((size_t)SEQ * 2048 * 2);
    unsigned short* qr_bf    = (unsigned short*)alloc((size_t)SEQ * QRANK * 2);
    unsigned short* q_b_bf   = (unsigned short*)alloc((size_t)3072 * QRANK * 2);
    unsigned short* kv_a_bf  = (unsigned short*)alloc((size_t)576 * HIDD * 2);
    unsigned short* o_w_bf   = (unsigned short*)alloc((size_t)HIDD * 2048 * 2);
    unsigned short* kv_b_bf  = (unsigned short*)alloc((size_t)4096 * 512 * 2);
    unsigned short* wkt      = (unsigned short*)alloc((size_t)16 * 512 * 128 * 2);
    size_t mark = off;
    // transients (dead after topk)
    float* qr    = (float*)alloc((size_t)SEQ * QRANK * 4);
    float* ccat  = (float*)alloc((size_t)SEQ * NCAT * 4);
    float* scores = (float*)alloc((size_t)SEQ * SEQ * 4);
    unsigned short* iqh = (unsigned short*)alloc((size_t)SEQ * 2048 * 2);
    unsigned short* iql = (unsigned short*)alloc((size_t)SEQ * 2048 * 2);
    unsigned short* ikh = (unsigned short*)alloc((size_t)SEQ * 128 * 2);
    unsigned short* ikl = (unsigned short*)alloc((size_t)SEQ * 128 * 2);
    // optional fast-path hi/lo precompute buffers (also transient)
    unsigned short* hidh  = (unsigned short*)alloc((size_t)HIDD * HIDD * 2);
    unsigned short* hidl  = (unsigned short*)alloc((size_t)HIDD * HIDD * 2);
    unsigned short* catwh = (unsigned short*)alloc((size_t)NCAT * HIDD * 2);
    unsigned short* catwl = (unsigned short*)alloc((size_t)NCAT * HIDD * 2);
    unsigned short* wqh   = (unsigned short*)alloc((size_t)HIDD * QRANK * 2);
    unsigned short* wql   = (unsigned short*)alloc((size_t)HIDD * QRANK * 2);
    unsigned short* qr_l  = (unsigned short*)alloc((size_t)SEQ * QRANK * 2);
    bool fast = (off <= ws_size);
    if (!fast) {
        hidh = hidl = catwh = catwl = wqh = wql = qr_l = nullptr;
    }
    // overlay region (alive after topk)
    off = mark;
    unsigned short* qabsb = (unsigned short*)alloc((size_t)SEQ * 16 * 512 * 2);
    unsigned short* ocomp = (unsigned short*)alloc((size_t)SEQ * 16 * 512 * 2);

    // weight converts + fused rope table (single launch)
    cvt_bf16_4_kernel<<<2048, 256, 0, stream>>>(
        q_b_w, 3072 * QRANK / 4, kv_a_w, 576 * HIDD / 4,
        o_w, HIDD * 2048 / 4, kv_b_w, 4096 * 512 / 4,
        q_b_bf, kv_a_bf, o_w_bf, kv_b_bf, cos_t, sin_t);
    wkt_kernel<<<dim3(16, 4), 256, 0, stream>>>(kv_b_w, wkt);
    if (fast)
        cvt_split3_kernel<<<2048, 256, 0, stream>>>(
            hidden, q_a_w, idx_wk_w, idx_wproj_w, idx_wq_b_w,
            hidh, hidl, catwh, catwl, wqh, wql);

    // fused cat-GEMM: ccat = hidden @ [q_a_w; idx_wk_w; 0.25*idx_wproj_w]^T  (split-MFMA)
    gemm_cat_split_kernel<<<dim3(16, 14), 256, 0, stream>>>(
        hidden, q_a_w, idx_wk_w, idx_wproj_w, hidh, hidl, catwh, catwl, ccat);

    // qr = rmsnorm(ccat[:, :1536]) -> f32 + bf16 hi (+ lo if fast)
    rmsnorm_kernel<<<SEQ, 256, 0, stream>>>(ccat, q_a_ln_w, qr, qr_bf, qr_l, QRANK, NCAT);

    // ik = rope(layernorm(ccat[:, 1536:1664])) -> hi/lo split
    ln_rope_split_kernel<<<SEQ, 64, 0, stream>>>(ccat + 1536, NCAT, idx_kn_w, idx_kn_b, cos_t, sin_t, ikh, ikl);

    // q = qr @ q_b_w^T (bf16 MFMA, fused per-head RoPE on [128:192))
    mfma_nt_kernel<unsigned short, float><<<dim3(16, 24, 1), 256, 0, stream>>>(
        qr_bf, q_b_bf, qbuf, SEQ, 3072, QRANK, QRANK, QRANK, 3072, 0L, 0L, 0L,
        cos_t, sin_t, 1);

    // ckv = hidden @ kv_a_w^T (MFMA, fused kpe RoPE on [512:576)); fused rmsnorm+khg
    mfma_nt_kernel<float, float><<<dim3(16, 5, 1), 256, 0, stream>>>(
        hidden, kv_a_bf, ckv, SEQ, 576, HIDD, HIDD, HIDD, 576, 0L, 0L, 0L,
        cos_t, sin_t, 2);
    rmsnorm_khg_kernel<<<SEQ, 256, 0, stream>>>(ckv, kv_a_ln_w, khg);

    // iq = rope(qr @ idx_wq_b_w^T) -> hi/lo split (split-MFMA, fused epilogue)
    gemm_iq_split_kernel<<<dim3(16, 16), 256, 0, stream>>>(
        qr, idx_wq_b_w, qr_bf, qr_l, wqh, wql, cos_t, sin_t, iqh, iql);

    // indexer scores (split-MFMA, B-hoisted) + topk
    idx_scores_mfma_kernel<<<dim3(32, 32), 256, 0, stream>>>(iqh, iql, ikh, ikl, ccat + 1664, NCAT, scores);
    topk_kernel<<<SEQ, 1024, 0, stream>>>(scores, sel);

    // q absorption (bf16 MFMA, batched per head)
    mfma_nt_kernel<float, unsigned short><<<dim3(16, 4, 16), 256, 0, stream>>>(
        qbuf, wkt, qabsb, SEQ, 512, 128, 3072, 128, 16 * 512,
        192L, 512L * 128L, 512L, nullptr, nullptr, 0);

    // MFMA flash attention over selected keys -> ocomp (normalized bf16)
    attn_mfma_kernel<<<SEQ, 256, 0, stream>>>(qabsb, qbuf, khg, sel, ocomp);

    // output projection (bf16 MFMA, batched)
    mfma_nt_kernel<unsigned short, unsigned short><<<dim3(16, 1, 16), 256, 0, stream>>>(
        ocomp, kv_b_bf + (size_t)128 * 512, attno_bf, SEQ, 128, 512,
        16 * 512, 512, 2048, 512L, 256L * 512L, 128L, nullptr, nullptr, 0);

    // out = attno @ o_w^T (bf16 MFMA)
    mfma_nt_kernel<unsigned short, float><<<dim3(16, 16, 1), 256, 0, stream>>>(
        attno_bf, o_w_bf, out, SEQ, HIDD, 2048, 2048, 2048, HIDD, 0L, 0L, 0L,
        nullptr, nullptr, 0);
}